// Round 1
// baseline (459.597 us; speedup 1.0000x reference)
//
#include <hip/hip_runtime.h>
#include <hip/hip_bf16.h>
#include <cstdint>

#define S4_H 256
#define S4_N 32
#define S4_L 4096
#define S4_B 16
#define S4_HN (S4_H * S4_N)

// ---------------- param kernel: w = exp(dt*A), Chat = 2*C*(w-1)/A ----------------
__global__ __launch_bounds__(256) void s4_param_kernel(
        const float* __restrict__ log_dt,
        const float* __restrict__ log_A_real,
        const float* __restrict__ A_imag,
        const float* __restrict__ C_real,
        const float* __restrict__ C_imag,
        float* __restrict__ P) {
    int idx = blockIdx.x * blockDim.x + threadIdx.x;
    if (idx >= S4_HN) return;
    int h = idx >> 5;
    float dt = expf(log_dt[h]);
    float Ar = -expf(log_A_real[idx]);
    float Ai = A_imag[idx];
    float dr = dt * Ar, di = dt * Ai;
    float er = expf(dr);
    float wr = er * cosf(di);
    float wi = er * sinf(di);
    // q = (w - 1) / A   (complex divide via conjugate)
    float inv = 1.0f / (Ar * Ar + Ai * Ai);
    float nr = wr - 1.0f, ni = wi;
    float qr = (nr * Ar + ni * Ai) * inv;
    float qi = (ni * Ar - nr * Ai) * inv;
    float Cr = C_real[idx], Ci = C_imag[idx];
    float ctr = Cr * qr - Ci * qi;
    float cti = Cr * qi + Ci * qr;
    P[idx]             = wr;
    P[idx + S4_HN]     = wi;
    P[idx + 2 * S4_HN] = 2.0f * ctr;   // y += cr*xr + ci*xi with ci = -2*Im(Ct)
    P[idx + 3 * S4_HN] = -2.0f * cti;
}

// tanh-approx GELU: x * sigmoid(1.59577*(x + 0.044715 x^3))
__device__ __forceinline__ float s4_gelu(float x) {
    float x3 = x * x * x;
    float z = 1.5957691216057308f * fmaf(0.044715f, x3, x);
    float e = __expf(-z);
    return x / (1.0f + e);
}

// round-to-nearest-even f32 -> bf16 (finite inputs)
__device__ __forceinline__ uint32_t s4_f2bf(float f) {
    uint32_t u = __float_as_uint(f);
    return (u + 0x7fffu + ((u >> 16) & 1u)) >> 16;
}

// sum over each 32-lane half via DPP; result valid in lanes 31 and 63
__device__ __forceinline__ float s4_rowsum32(float v) {
    v += __int_as_float(__builtin_amdgcn_update_dpp(0, __float_as_int(v), 0x111, 0xf, 0xf, false)); // row_shr:1
    v += __int_as_float(__builtin_amdgcn_update_dpp(0, __float_as_int(v), 0x112, 0xf, 0xf, false)); // row_shr:2
    v += __int_as_float(__builtin_amdgcn_update_dpp(0, __float_as_int(v), 0x114, 0xf, 0xf, false)); // row_shr:4
    v += __int_as_float(__builtin_amdgcn_update_dpp(0, __float_as_int(v), 0x118, 0xf, 0xf, false)); // row_shr:8
    v += __int_as_float(__builtin_amdgcn_update_dpp(0, __float_as_int(v), 0x142, 0xf, 0xf, false)); // row_bcast15
    return v;
}

// ---------------- scan kernel: per (b,h) recurrence, fused D-skip + GELU -> bf16 ----------------
__global__ __launch_bounds__(256) void s4_scan_kernel(
        const float* __restrict__ u,
        const float* __restrict__ P,
        const float* __restrict__ D,
        uint32_t* __restrict__ g) {
    __shared__ float ubuf[8][64];
    __shared__ float ybuf[8][64];
    const int tid = threadIdx.x;
    const int grp = tid >> 5;      // 8 groups (b,h) per block
    const int n = tid & 31;        // state index
    const int G = blockIdx.x * 8 + grp;          // 0..B*H-1
    const int h = G & (S4_H - 1);
    const int pidx = (h << 5) + n;
    const float wr = P[pidx];
    const float wi = P[pidx + S4_HN];
    const float cr = P[pidx + 2 * S4_HN];
    const float ci = P[pidx + 3 * S4_HN];
    const float Dh = D[h];
    const float* __restrict__ up = u + (size_t)G * S4_L;
    uint32_t* __restrict__ gp = g + (size_t)G * (S4_L / 2);
    float xr = 0.0f, xi = 0.0f;
    for (int c = 0; c < 64; ++c) {
        // stage 64 u values (coalesced float2 per lane)
        float2 u2 = *(const float2*)(up + c * 64 + n * 2);
        *(float2*)(&ubuf[grp][n * 2]) = u2;
        __syncthreads();
        #pragma unroll 16
        for (int t = 0; t < 64; ++t) {
            float uv = ubuf[grp][t];                       // broadcast read
            float nxr = fmaf(wr, xr, fmaf(-wi, xi, uv));   // wr*xr - wi*xi + u
            float nxi = fmaf(wr, xi, wi * xr);
            xr = nxr; xi = nxi;
            float cc = fmaf(cr, xr, ci * xi);
            cc = s4_rowsum32(cc);
            if (n == 31) ybuf[grp][t] = cc;
        }
        __syncthreads();
        // flush: y += D*u, gelu, bf16 pack, coalesced store
        float2 yc = *(const float2*)(&ybuf[grp][n * 2]);
        float2 uu = *(const float2*)(&ubuf[grp][n * 2]);
        float g0 = s4_gelu(fmaf(Dh, uu.x, yc.x));
        float g1 = s4_gelu(fmaf(Dh, uu.y, yc.y));
        gp[c * 32 + n] = s4_f2bf(g0) | (s4_f2bf(g1) << 16);
        __syncthreads();
    }
}

// ---------------- GEMM: out[b] = W @ G[b] + bias   (M=256, K=256, N=4096 per b) ----------------
__global__ __launch_bounds__(256) void s4_gemm_kernel(
        const uint32_t* __restrict__ g,   // bf16 pairs, (B,H,L)
        const float* __restrict__ W,      // (H,H) row-major: W[h'][h]
        const float* __restrict__ bias,
        float* __restrict__ out) {        // (B,H,L)
    __shared__ float Wl[64][17];
    __shared__ float Gl[16][132];
    const int tid = threadIdx.x;
    const int b = blockIdx.z;
    const int hp0 = blockIdx.y << 6;   // h' tile base (64 rows)
    const int l0 = blockIdx.x << 7;    // l tile base (128 cols)
    const int r0 = (tid >> 5) << 3;    // 8 rows per thread-group
    const int lc = (tid & 31) << 2;    // 4 cols per thread
    float acc[8][4] = {};
    for (int h0 = 0; h0 < S4_H; h0 += 16) {
        {   // stage W tile 64x16
            int row = tid >> 2, c4 = (tid & 3) << 2;
            float4 wv = *(const float4*)(W + (size_t)(hp0 + row) * S4_H + h0 + c4);
            *(float4*)(&Wl[row][c4]) = wv;
        }
        {   // stage G tile 16x128 (bf16 -> f32)
            int row = tid >> 4, c8 = (tid & 15) << 3;
            size_t gi = ((size_t)((b << 8) + h0 + row) * S4_L + l0 + c8) >> 1;
            uint4 gv = *(const uint4*)(g + gi);
            float* dst = &Gl[row][c8];
            dst[0] = __uint_as_float(gv.x << 16);
            dst[1] = __uint_as_float(gv.x & 0xffff0000u);
            dst[2] = __uint_as_float(gv.y << 16);
            dst[3] = __uint_as_float(gv.y & 0xffff0000u);
            dst[4] = __uint_as_float(gv.z << 16);
            dst[5] = __uint_as_float(gv.z & 0xffff0000u);
            dst[6] = __uint_as_float(gv.w << 16);
            dst[7] = __uint_as_float(gv.w & 0xffff0000u);
        }
        __syncthreads();
        #pragma unroll
        for (int kk = 0; kk < 16; ++kk) {
            float4 bv = *(const float4*)(&Gl[kk][lc]);
            #pragma unroll
            for (int i = 0; i < 8; ++i) {
                float av = Wl[r0 + i][kk];
                acc[i][0] = fmaf(av, bv.x, acc[i][0]);
                acc[i][1] = fmaf(av, bv.y, acc[i][1]);
                acc[i][2] = fmaf(av, bv.z, acc[i][2]);
                acc[i][3] = fmaf(av, bv.w, acc[i][3]);
            }
        }
        __syncthreads();
    }
    #pragma unroll
    for (int i = 0; i < 8; ++i) {
        float bo = bias[hp0 + r0 + i];
        float4 o;
        o.x = acc[i][0] + bo; o.y = acc[i][1] + bo;
        o.z = acc[i][2] + bo; o.w = acc[i][3] + bo;
        *(float4*)(out + ((size_t)((b << 8) + hp0 + r0 + i)) * S4_L + l0 + lc) = o;
    }
}

extern "C" void kernel_launch(void* const* d_in, const int* in_sizes, int n_in,
                              void* d_out, int out_size, void* d_ws, size_t ws_size,
                              hipStream_t stream) {
    const float* inp        = (const float*)d_in[0]; // (B,CIN,F,L) == (B,H,L)
    const float* log_dt     = (const float*)d_in[1];
    const float* log_A_real = (const float*)d_in[2];
    const float* A_imag     = (const float*)d_in[3];
    const float* C_real     = (const float*)d_in[4];
    const float* C_imag     = (const float*)d_in[5];
    const float* D          = (const float*)d_in[6];
    const float* W_out      = (const float*)d_in[7];
    const float* b_out      = (const float*)d_in[8];
    float* out = (float*)d_out;

    float* P = (float*)d_ws;                                        // 4*H*N f32 = 128KB
    uint32_t* g = (uint32_t*)((char*)d_ws + 4 * S4_HN * sizeof(float)); // bf16 (B,H,L) = 33.5MB

    hipLaunchKernelGGL(s4_param_kernel, dim3(S4_HN / 256), dim3(256), 0, stream,
                       log_dt, log_A_real, A_imag, C_real, C_imag, P);
    hipLaunchKernelGGL(s4_scan_kernel, dim3(S4_B * S4_H / 8), dim3(256), 0, stream,
                       inp, P, D, g);
    hipLaunchKernelGGL(s4_gemm_kernel, dim3(S4_L / 128, S4_H / 64, S4_B), dim3(256), 0, stream,
                       g, W_out, b_out, out);
}

// Round 2
// 165.022 us; speedup vs baseline: 2.7851x; 2.7851x over previous
//
#include <hip/hip_runtime.h>
#include <hip/hip_bf16.h>
#include <cstdint>

#define S4_H 256
#define S4_N 32
#define S4_L 4096
#define S4_B 16
#define S4_T 64
#define S4_C 64

typedef __attribute__((ext_vector_type(8))) short bf16x8;
typedef __attribute__((ext_vector_type(4))) float f32x4;

// round-to-nearest-even f32 -> bf16 (finite inputs)
__device__ __forceinline__ uint32_t s4_f2bf(float f) {
    uint32_t u = __float_as_uint(f);
    return (u + 0x7fffu + ((u >> 16) & 1u)) >> 16;
}

// tanh-approx GELU: x * sigmoid(1.59577*(x + 0.044715 x^3))
__device__ __forceinline__ float s4_gelu(float x) {
    float x3 = x * x * x;
    float z = 1.5957691216057308f * fmaf(0.044715f, x3, x);
    float e = __expf(-z);
    return x / (1.0f + e);
}

// sum within each 32-lane half via DPP; result valid in lanes 31 and 63
__device__ __forceinline__ float s4_rowsum32(float v) {
    v += __int_as_float(__builtin_amdgcn_update_dpp(0, __float_as_int(v), 0x111, 0xf, 0xf, false)); // row_shr:1
    v += __int_as_float(__builtin_amdgcn_update_dpp(0, __float_as_int(v), 0x112, 0xf, 0xf, false)); // row_shr:2
    v += __int_as_float(__builtin_amdgcn_update_dpp(0, __float_as_int(v), 0x114, 0xf, 0xf, false)); // row_shr:4
    v += __int_as_float(__builtin_amdgcn_update_dpp(0, __float_as_int(v), 0x118, 0xf, 0xf, false)); // row_shr:8
    v += __int_as_float(__builtin_amdgcn_update_dpp(0, __float_as_int(v), 0x142, 0xf, 0xf, false)); // row_bcast15
    return v;
}

// ---------------- table kernel: per-h E, Toeplitz(K), V tables (bf16) + w^T ----------------
__global__ __launch_bounds__(64) void s4_tab_kernel(
        const float* __restrict__ log_dt, const float* __restrict__ log_A_real,
        const float* __restrict__ A_imag, const float* __restrict__ C_real,
        const float* __restrict__ C_imag,
        float* __restrict__ wT, ushort* __restrict__ Ebf,
        ushort* __restrict__ TMbf, ushort* __restrict__ Vbf) {
    const int h = blockIdx.x, tid = threadIdx.x, n = tid & 31;
    __shared__ float Ksh[S4_T];
    const int idx = h * 32 + n;
    float dt = expf(log_dt[h]);
    float Ar = -expf(log_A_real[idx]);
    float Ai = A_imag[idx];
    float er = expf(dt * Ar);
    float wr = er * cosf(dt * Ai);
    float wi = er * sinf(dt * Ai);
    float inv = 1.0f / (Ar * Ar + Ai * Ai);
    float mr = wr - 1.0f, mi = wi;
    float qr = (mr * Ar + mi * Ai) * inv;
    float qi = (mi * Ar - mr * Ai) * inv;
    float Cr = C_real[idx], Ci = C_imag[idx];
    float cr = 2.0f * (Cr * qr - Ci * qi);    //  2*Re(Chat)
    float ci = -2.0f * (Cr * qi + Ci * qr);   // -2*Im(Chat)
    ushort* Eh = Ebf + h * 4096;
    ushort* Vh = Vbf + h * 4096;
    float pr = 1.0f, pi = 0.0f;               // p = w^t
    for (int t = 0; t < S4_T; ++t) {
        if (tid < 32) {
            Eh[(2 * n) * 64 + (63 - t)]     = (ushort)s4_f2bf(pr);
            Eh[(2 * n + 1) * 64 + (63 - t)] = (ushort)s4_f2bf(pi);
        }
        float kt = s4_rowsum32(fmaf(cr, pr, ci * pi));   // K[t] = 2Re(sum Chat w^t)
        if (tid == 31) Ksh[t] = kt;
        float Qr = pr * wr - pi * wi;          // Q = w^{t+1}
        float Qi = pr * wi + pi * wr;
        if (tid < 32) {
            Vh[t * 64 + 2 * n]     = (ushort)s4_f2bf(fmaf(cr, Qr, ci * Qi));   //  2Re(Chat Q)
            Vh[t * 64 + 2 * n + 1] = (ushort)s4_f2bf(fmaf(ci, Qr, -cr * Qi));  // -2Im(Chat Q)
        }
        pr = Qr; pi = Qi;
    }
    if (tid < 32) { wT[idx] = pr; wT[8192 + idx] = pi; }   // w^64
    __syncthreads();
    ushort* TMh = TMbf + h * 4096;
    for (int e = tid; e < 4096; e += 64) {
        int to = e >> 6, ti = e & 63;
        TMh[e] = (ti <= to) ? (ushort)s4_f2bf(Ksh[to - ti]) : (ushort)0;
    }
}

// ---------------- fused chunk-parallel scan: one block per (b,h) ----------------
// Phase1: S = E @ U (MFMA).  Phase2: serial chunk scan (1 wave).  Phase3: Y = TM@U + V@X,
// then y += D*u, GELU, bf16 pack -> g (B,H,L).
__global__ __launch_bounds__(256) void s4_scan_fused(
        const float* __restrict__ u, const float* __restrict__ wT,
        const ushort* __restrict__ Ebf, const ushort* __restrict__ TMbf,
        const ushort* __restrict__ Vbf, const float* __restrict__ D,
        uint32_t* __restrict__ g) {
    __shared__ char UbfB[8192];        // u as bf16, XOR-swizzled by (c&7)<<4
    __shared__ float Ssh[64][64];      // [c][r] chunk sums
    __shared__ char XbfB[8192];        // chunk entry states bf16 [c][k], same swizzle
    const int tid = threadIdx.x;
    const int bh = blockIdx.x;
    const int h = bh & (S4_H - 1);
    const int w = tid >> 6, lane = tid & 63;
    const int l15 = lane & 15, lg = lane >> 4;

    // ---- stage U: 16 f32 per thread -> bf16 LDS ----
    const float* up = u + (size_t)bh * S4_L;
    {
        const float4* uf = (const float4*)(up) + tid * 4;
        #pragma unroll
        for (int j = 0; j < 4; ++j) {
            float4 v = uf[j];
            uint2 pk;
            pk.x = s4_f2bf(v.x) | (s4_f2bf(v.y) << 16);
            pk.y = s4_f2bf(v.z) | (s4_f2bf(v.w) << 16);
            int o = tid * 32 + j * 8;
            *(uint2*)(UbfB + (o ^ (((o >> 7) & 7) << 4))) = pk;
        }
    }
    // ---- A-fragments (row = 16w + l15, k0 = lg*8) straight from global (L2-hot) ----
    const int arow = 16 * w + l15;
    const size_t tb = (size_t)h * 4096 + (size_t)arow * 64 + lg * 8;
    bf16x8 eA0 = *(const bf16x8*)(Ebf + tb);
    bf16x8 eA1 = *(const bf16x8*)(Ebf + tb + 32);
    bf16x8 tA0 = *(const bf16x8*)(TMbf + tb);
    bf16x8 tA1 = *(const bf16x8*)(TMbf + tb + 32);
    bf16x8 vA0 = *(const bf16x8*)(Vbf + tb);
    bf16x8 vA1 = *(const bf16x8*)(Vbf + tb + 32);
    __syncthreads();

    // ---- phase 1: S = E @ U ----
    bf16x8 ufr[4][2];
    #pragma unroll
    for (int ct = 0; ct < 4; ++ct) {
        int c = ct * 16 + l15;
        int swz = (c & 7) << 4;
        ufr[ct][0] = *(const bf16x8*)(UbfB + c * 128 + ((lg * 16) ^ swz));
        ufr[ct][1] = *(const bf16x8*)(UbfB + c * 128 + ((64 + lg * 16) ^ swz));
        f32x4 acc = {0.f, 0.f, 0.f, 0.f};
        acc = __builtin_amdgcn_mfma_f32_16x16x32_bf16(eA0, ufr[ct][0], acc, 0, 0, 0);
        acc = __builtin_amdgcn_mfma_f32_16x16x32_bf16(eA1, ufr[ct][1], acc, 0, 0, 0);
        *(f32x4*)(&Ssh[c][16 * w + lg * 4]) = acc;   // rows r = 16w + lg*4 + j
    }
    __syncthreads();

    // ---- phase 2: X[c] = state before chunk c; x <- wT*x + S[c] ----
    if (tid < 32) {
        float wtr = wT[h * 32 + tid], wti = wT[8192 + h * 32 + tid];
        float xr = 0.f, xi = 0.f;
        for (int c = 0; c < S4_C; ++c) {
            int o = c * 128 + tid * 4;
            *(uint32_t*)(XbfB + (o ^ (((c & 7) << 4)))) = s4_f2bf(xr) | (s4_f2bf(xi) << 16);
            float2 s2 = *(const float2*)(&Ssh[c][2 * tid]);
            float nr2 = fmaf(wtr, xr, fmaf(-wti, xi, s2.x));
            float ni2 = fmaf(wtr, xi, fmaf(wti, xr, s2.y));
            xr = nr2; xi = ni2;
        }
    }
    __syncthreads();

    // ---- phase 3: Y = TM@U + V@X, fused epilogue ----
    const float Dh = D[h];
    uint32_t* gp = g + (size_t)bh * (S4_L / 2);
    #pragma unroll
    for (int ct = 0; ct < 4; ++ct) {
        int c = ct * 16 + l15;
        int swz = (c & 7) << 4;
        bf16x8 xb0 = *(const bf16x8*)(XbfB + c * 128 + ((lg * 16) ^ swz));
        bf16x8 xb1 = *(const bf16x8*)(XbfB + c * 128 + ((64 + lg * 16) ^ swz));
        f32x4 y = {0.f, 0.f, 0.f, 0.f};
        y = __builtin_amdgcn_mfma_f32_16x16x32_bf16(tA0, ufr[ct][0], y, 0, 0, 0);
        y = __builtin_amdgcn_mfma_f32_16x16x32_bf16(tA1, ufr[ct][1], y, 0, 0, 0);
        y = __builtin_amdgcn_mfma_f32_16x16x32_bf16(vA0, xb0, y, 0, 0, 0);
        y = __builtin_amdgcn_mfma_f32_16x16x32_bf16(vA1, xb1, y, 0, 0, 0);
        int t0 = 16 * w + lg * 4;                       // rows t = t0..t0+3, l = c*64 + t
        uint2 upk = *(const uint2*)(UbfB + c * 128 + ((t0 * 2) ^ swz));
        float u0 = __uint_as_float(upk.x << 16);
        float u1 = __uint_as_float(upk.x & 0xffff0000u);
        float u2 = __uint_as_float(upk.y << 16);
        float u3 = __uint_as_float(upk.y & 0xffff0000u);
        float g0 = s4_gelu(fmaf(Dh, u0, y[0]));
        float g1 = s4_gelu(fmaf(Dh, u1, y[1]));
        float g2 = s4_gelu(fmaf(Dh, u2, y[2]));
        float g3 = s4_gelu(fmaf(Dh, u3, y[3]));
        uint2 opk;
        opk.x = s4_f2bf(g0) | (s4_f2bf(g1) << 16);
        opk.y = s4_f2bf(g2) | (s4_f2bf(g3) << 16);
        *(uint2*)(gp + (c * 64 + t0) / 2) = opk;
    }
}

// ---------------- GEMM: out[b] = W @ G[b] + bias   (unchanged, proven) ----------------
__global__ __launch_bounds__(256) void s4_gemm_kernel(
        const uint32_t* __restrict__ g,   // bf16 pairs, (B,H,L)
        const float* __restrict__ W,      // (H,H) row-major: W[h'][h]
        const float* __restrict__ bias,
        float* __restrict__ out) {        // (B,H,L)
    __shared__ float Wl[64][17];
    __shared__ float Gl[16][132];
    const int tid = threadIdx.x;
    const int b = blockIdx.z;
    const int hp0 = blockIdx.y << 6;
    const int l0 = blockIdx.x << 7;
    const int r0 = (tid >> 5) << 3;
    const int lc = (tid & 31) << 2;
    float acc[8][4] = {};
    for (int h0 = 0; h0 < S4_H; h0 += 16) {
        {
            int row = tid >> 2, c4 = (tid & 3) << 2;
            float4 wv = *(const float4*)(W + (size_t)(hp0 + row) * S4_H + h0 + c4);
            *(float4*)(&Wl[row][c4]) = wv;
        }
        {
            int row = tid >> 4, c8 = (tid & 15) << 3;
            size_t gi = ((size_t)((b << 8) + h0 + row) * S4_L + l0 + c8) >> 1;
            uint4 gv = *(const uint4*)(g + gi);
            float* dst = &Gl[row][c8];
            dst[0] = __uint_as_float(gv.x << 16);
            dst[1] = __uint_as_float(gv.x & 0xffff0000u);
            dst[2] = __uint_as_float(gv.y << 16);
            dst[3] = __uint_as_float(gv.y & 0xffff0000u);
            dst[4] = __uint_as_float(gv.z << 16);
            dst[5] = __uint_as_float(gv.z & 0xffff0000u);
            dst[6] = __uint_as_float(gv.w << 16);
            dst[7] = __uint_as_float(gv.w & 0xffff0000u);
        }
        __syncthreads();
        #pragma unroll
        for (int kk = 0; kk < 16; ++kk) {
            float4 bv = *(const float4*)(&Gl[kk][lc]);
            #pragma unroll
            for (int i = 0; i < 8; ++i) {
                float av = Wl[r0 + i][kk];
                acc[i][0] = fmaf(av, bv.x, acc[i][0]);
                acc[i][1] = fmaf(av, bv.y, acc[i][1]);
                acc[i][2] = fmaf(av, bv.z, acc[i][2]);
                acc[i][3] = fmaf(av, bv.w, acc[i][3]);
            }
        }
        __syncthreads();
    }
    #pragma unroll
    for (int i = 0; i < 8; ++i) {
        float bo = bias[hp0 + r0 + i];
        float4 o;
        o.x = acc[i][0] + bo; o.y = acc[i][1] + bo;
        o.z = acc[i][2] + bo; o.w = acc[i][3] + bo;
        *(float4*)(out + ((size_t)((b << 8) + hp0 + r0 + i)) * S4_L + l0 + lc) = o;
    }
}

extern "C" void kernel_launch(void* const* d_in, const int* in_sizes, int n_in,
                              void* d_out, int out_size, void* d_ws, size_t ws_size,
                              hipStream_t stream) {
    const float* inp        = (const float*)d_in[0]; // (B,CIN,F,L) == (B,H,L)
    const float* log_dt     = (const float*)d_in[1];
    const float* log_A_real = (const float*)d_in[2];
    const float* A_imag     = (const float*)d_in[3];
    const float* C_real     = (const float*)d_in[4];
    const float* C_imag     = (const float*)d_in[5];
    const float* D          = (const float*)d_in[6];
    const float* W_out      = (const float*)d_in[7];
    const float* b_out      = (const float*)d_in[8];
    float* out = (float*)d_out;

    char* wsc = (char*)d_ws;
    float* wT     = (float*)wsc;                                  // 64 KB (wTr | wTi planes)
    ushort* Ebf   = (ushort*)(wsc + (64 << 10));                  // 2 MB
    ushort* TMbf  = (ushort*)(wsc + (64 << 10) + (2 << 20));      // 2 MB
    ushort* Vbf   = (ushort*)(wsc + (64 << 10) + (4 << 20));      // 2 MB
    uint32_t* g   = (uint32_t*)(wsc + (64 << 10) + (6 << 20));    // 33.5 MB bf16 (B,H,L)

    hipLaunchKernelGGL(s4_tab_kernel, dim3(S4_H), dim3(64), 0, stream,
                       log_dt, log_A_real, A_imag, C_real, C_imag, wT, Ebf, TMbf, Vbf);
    hipLaunchKernelGGL(s4_scan_fused, dim3(S4_B * S4_H), dim3(256), 0, stream,
                       inp, wT, Ebf, TMbf, Vbf, D, g);
    hipLaunchKernelGGL(s4_gemm_kernel, dim3(S4_L / 128, S4_H / 64, S4_B), dim3(256), 0, stream,
                       g, W_out, b_out, out);
}

// Round 3
// 90.515 us; speedup vs baseline: 5.0776x; 1.8231x over previous
//
#include <hip/hip_runtime.h>
#include <hip/hip_bf16.h>
#include <cstdint>

#define S4_H 256
#define S4_N 32
#define S4_L 4096
#define S4_B 16
#define S4_T 64
#define S4_C 64

typedef __attribute__((ext_vector_type(8))) short bf16x8;
typedef __attribute__((ext_vector_type(4))) float f32x4;

// round-to-nearest-even f32 -> bf16 (finite inputs)
__device__ __forceinline__ uint32_t s4_f2bf(float f) {
    uint32_t u = __float_as_uint(f);
    return (u + 0x7fffu + ((u >> 16) & 1u)) >> 16;
}

// tanh-approx GELU: x * sigmoid(1.59577*(x + 0.044715 x^3))
__device__ __forceinline__ float s4_gelu(float x) {
    float x3 = x * x * x;
    float z = 1.5957691216057308f * fmaf(0.044715f, x3, x);
    float e = __expf(-z);
    return x / (1.0f + e);
}

// sum within each 32-lane half via DPP; result valid in lanes 31 and 63
__device__ __forceinline__ float s4_rowsum32(float v) {
    v += __int_as_float(__builtin_amdgcn_update_dpp(0, __float_as_int(v), 0x111, 0xf, 0xf, false)); // row_shr:1
    v += __int_as_float(__builtin_amdgcn_update_dpp(0, __float_as_int(v), 0x112, 0xf, 0xf, false)); // row_shr:2
    v += __int_as_float(__builtin_amdgcn_update_dpp(0, __float_as_int(v), 0x114, 0xf, 0xf, false)); // row_shr:4
    v += __int_as_float(__builtin_amdgcn_update_dpp(0, __float_as_int(v), 0x118, 0xf, 0xf, false)); // row_shr:8
    v += __int_as_float(__builtin_amdgcn_update_dpp(0, __float_as_int(v), 0x142, 0xf, 0xf, false)); // row_bcast15
    return v;
}

// ---------------- table kernel: per-h E, Toeplitz(K), V tables (bf16) + w^T ----------------
__global__ __launch_bounds__(64) void s4_tab_kernel(
        const float* __restrict__ log_dt, const float* __restrict__ log_A_real,
        const float* __restrict__ A_imag, const float* __restrict__ C_real,
        const float* __restrict__ C_imag,
        float* __restrict__ wT, ushort* __restrict__ Ebf,
        ushort* __restrict__ TMbf, ushort* __restrict__ Vbf) {
    const int h = blockIdx.x, tid = threadIdx.x, n = tid & 31;
    __shared__ float Ksh[S4_T];
    const int idx = h * 32 + n;
    float dt = expf(log_dt[h]);
    float Ar = -expf(log_A_real[idx]);
    float Ai = A_imag[idx];
    float er = expf(dt * Ar);
    float wr = er * cosf(dt * Ai);
    float wi = er * sinf(dt * Ai);
    float inv = 1.0f / (Ar * Ar + Ai * Ai);
    float mr = wr - 1.0f, mi = wi;
    float qr = (mr * Ar + mi * Ai) * inv;
    float qi = (mi * Ar - mr * Ai) * inv;
    float Cr = C_real[idx], Ci = C_imag[idx];
    float cr = 2.0f * (Cr * qr - Ci * qi);    //  2*Re(Chat)
    float ci = -2.0f * (Cr * qi + Ci * qr);   // -2*Im(Chat)
    ushort* Eh = Ebf + h * 4096;
    ushort* Vh = Vbf + h * 4096;
    float pr = 1.0f, pi = 0.0f;               // p = w^t
    for (int t = 0; t < S4_T; ++t) {
        if (tid < 32) {
            Eh[(2 * n) * 64 + (63 - t)]     = (ushort)s4_f2bf(pr);
            Eh[(2 * n + 1) * 64 + (63 - t)] = (ushort)s4_f2bf(pi);
        }
        float kt = s4_rowsum32(fmaf(cr, pr, ci * pi));   // K[t] = 2Re(sum Chat w^t)
        if (tid == 31) Ksh[t] = kt;
        float Qr = pr * wr - pi * wi;          // Q = w^{t+1}
        float Qi = pr * wi + pi * wr;
        if (tid < 32) {
            Vh[t * 64 + 2 * n]     = (ushort)s4_f2bf(fmaf(cr, Qr, ci * Qi));   //  2Re(Chat Q)
            Vh[t * 64 + 2 * n + 1] = (ushort)s4_f2bf(fmaf(ci, Qr, -cr * Qi));  // -2Im(Chat Q)
        }
        pr = Qr; pi = Qi;
    }
    if (tid < 32) { wT[idx] = pr; wT[8192 + idx] = pi; }   // w^64
    __syncthreads();
    ushort* TMh = TMbf + h * 4096;
    for (int e = tid; e < 4096; e += 64) {
        int to = e >> 6, ti = e & 63;
        TMh[e] = (ti <= to) ? (ushort)s4_f2bf(Ksh[to - ti]) : (ushort)0;
    }
}

// ---------------- W f32 -> octet-interleaved bf16: Wp[k/8][m][8] ----------------
__global__ __launch_bounds__(256) void s4_wconv(const float* __restrict__ W,
                                               ushort* __restrict__ Wp) {
    const int m = threadIdx.x, ko = blockIdx.x;
    const float* src = W + (size_t)m * S4_H + ko * 8;
    float4 a = *(const float4*)src;
    float4 b = *(const float4*)(src + 4);
    uint4 pk;
    pk.x = s4_f2bf(a.x) | (s4_f2bf(a.y) << 16);
    pk.y = s4_f2bf(a.z) | (s4_f2bf(a.w) << 16);
    pk.z = s4_f2bf(b.x) | (s4_f2bf(b.y) << 16);
    pk.w = s4_f2bf(b.z) | (s4_f2bf(b.w) << 16);
    *(uint4*)(Wp + ((size_t)ko * S4_H + m) * 8) = pk;
}

// ---------------- fused chunk-parallel scan: one block per (b,h) (unchanged) ----------------
__global__ __launch_bounds__(256) void s4_scan_fused(
        const float* __restrict__ u, const float* __restrict__ wT,
        const ushort* __restrict__ Ebf, const ushort* __restrict__ TMbf,
        const ushort* __restrict__ Vbf, const float* __restrict__ D,
        uint32_t* __restrict__ g) {
    __shared__ char UbfB[8192];        // u as bf16, XOR-swizzled by (c&7)<<4
    __shared__ float Ssh[64][64];      // [c][r] chunk sums
    __shared__ char XbfB[8192];        // chunk entry states bf16 [c][k], same swizzle
    const int tid = threadIdx.x;
    const int bh = blockIdx.x;
    const int h = bh & (S4_H - 1);
    const int w = tid >> 6, lane = tid & 63;
    const int l15 = lane & 15, lg = lane >> 4;

    const float* up = u + (size_t)bh * S4_L;
    {
        const float4* uf = (const float4*)(up) + tid * 4;
        #pragma unroll
        for (int j = 0; j < 4; ++j) {
            float4 v = uf[j];
            uint2 pk;
            pk.x = s4_f2bf(v.x) | (s4_f2bf(v.y) << 16);
            pk.y = s4_f2bf(v.z) | (s4_f2bf(v.w) << 16);
            int o = tid * 32 + j * 8;
            *(uint2*)(UbfB + (o ^ (((o >> 7) & 7) << 4))) = pk;
        }
    }
    const int arow = 16 * w + l15;
    const size_t tb = (size_t)h * 4096 + (size_t)arow * 64 + lg * 8;
    bf16x8 eA0 = *(const bf16x8*)(Ebf + tb);
    bf16x8 eA1 = *(const bf16x8*)(Ebf + tb + 32);
    bf16x8 tA0 = *(const bf16x8*)(TMbf + tb);
    bf16x8 tA1 = *(const bf16x8*)(TMbf + tb + 32);
    bf16x8 vA0 = *(const bf16x8*)(Vbf + tb);
    bf16x8 vA1 = *(const bf16x8*)(Vbf + tb + 32);
    __syncthreads();

    bf16x8 ufr[4][2];
    #pragma unroll
    for (int ct = 0; ct < 4; ++ct) {
        int c = ct * 16 + l15;
        int swz = (c & 7) << 4;
        ufr[ct][0] = *(const bf16x8*)(UbfB + c * 128 + ((lg * 16) ^ swz));
        ufr[ct][1] = *(const bf16x8*)(UbfB + c * 128 + ((64 + lg * 16) ^ swz));
        f32x4 acc = {0.f, 0.f, 0.f, 0.f};
        acc = __builtin_amdgcn_mfma_f32_16x16x32_bf16(eA0, ufr[ct][0], acc, 0, 0, 0);
        acc = __builtin_amdgcn_mfma_f32_16x16x32_bf16(eA1, ufr[ct][1], acc, 0, 0, 0);
        *(f32x4*)(&Ssh[c][16 * w + lg * 4]) = acc;
    }
    __syncthreads();

    if (tid < 32) {
        float wtr = wT[h * 32 + tid], wti = wT[8192 + h * 32 + tid];
        float xr = 0.f, xi = 0.f;
        for (int c = 0; c < S4_C; ++c) {
            int o = c * 128 + tid * 4;
            *(uint32_t*)(XbfB + (o ^ (((c & 7) << 4)))) = s4_f2bf(xr) | (s4_f2bf(xi) << 16);
            float2 s2 = *(const float2*)(&Ssh[c][2 * tid]);
            float nr2 = fmaf(wtr, xr, fmaf(-wti, xi, s2.x));
            float ni2 = fmaf(wtr, xi, fmaf(wti, xr, s2.y));
            xr = nr2; xi = ni2;
        }
    }
    __syncthreads();

    const float Dh = D[h];
    uint32_t* gp = g + (size_t)bh * (S4_L / 2);
    #pragma unroll
    for (int ct = 0; ct < 4; ++ct) {
        int c = ct * 16 + l15;
        int swz = (c & 7) << 4;
        bf16x8 xb0 = *(const bf16x8*)(XbfB + c * 128 + ((lg * 16) ^ swz));
        bf16x8 xb1 = *(const bf16x8*)(XbfB + c * 128 + ((64 + lg * 16) ^ swz));
        f32x4 y = {0.f, 0.f, 0.f, 0.f};
        y = __builtin_amdgcn_mfma_f32_16x16x32_bf16(tA0, ufr[ct][0], y, 0, 0, 0);
        y = __builtin_amdgcn_mfma_f32_16x16x32_bf16(tA1, ufr[ct][1], y, 0, 0, 0);
        y = __builtin_amdgcn_mfma_f32_16x16x32_bf16(vA0, xb0, y, 0, 0, 0);
        y = __builtin_amdgcn_mfma_f32_16x16x32_bf16(vA1, xb1, y, 0, 0, 0);
        int t0 = 16 * w + lg * 4;
        uint2 upk = *(const uint2*)(UbfB + c * 128 + ((t0 * 2) ^ swz));
        float u0 = __uint_as_float(upk.x << 16);
        float u1 = __uint_as_float(upk.x & 0xffff0000u);
        float u2 = __uint_as_float(upk.y << 16);
        float u3 = __uint_as_float(upk.y & 0xffff0000u);
        float g0 = s4_gelu(fmaf(Dh, u0, y[0]));
        float g1 = s4_gelu(fmaf(Dh, u1, y[1]));
        float g2 = s4_gelu(fmaf(Dh, u2, y[2]));
        float g3 = s4_gelu(fmaf(Dh, u3, y[3]));
        uint2 opk;
        opk.x = s4_f2bf(g0) | (s4_f2bf(g1) << 16);
        opk.y = s4_f2bf(g2) | (s4_f2bf(g3) << 16);
        *(uint2*)(gp + (c * 64 + t0) / 2) = opk;
    }
}

// ---------------- octet transpose: g (B,H,L) -> gP[b][h/8][l][8] (all bf16) ----------------
__global__ __launch_bounds__(256) void s4_g2p(const ushort* __restrict__ g,
                                              ushort* __restrict__ gP) {
    const int ho = blockIdx.x, b = blockIdx.y;
    const int t = threadIdx.x;
    const ushort* gbase = g + (size_t)(b * S4_H + ho * 8) * S4_L;
    ushort* pbase = gP + (size_t)(b * 32 + ho) * S4_L * 8;
    for (int it = 0; it < 8; ++it) {
        int l = it * 512 + t * 2;
        uint32_t r[8];
        #pragma unroll
        for (int i = 0; i < 8; ++i)
            r[i] = *(const uint32_t*)(gbase + (size_t)i * S4_L + l);
        uint4 lo, hi;
        lo.x = (r[0] & 0xffffu) | (r[1] << 16);
        lo.y = (r[2] & 0xffffu) | (r[3] << 16);
        lo.z = (r[4] & 0xffffu) | (r[5] << 16);
        lo.w = (r[6] & 0xffffu) | (r[7] << 16);
        hi.x = (r[0] >> 16) | (r[1] & 0xffff0000u);
        hi.y = (r[2] >> 16) | (r[3] & 0xffff0000u);
        hi.z = (r[4] >> 16) | (r[5] & 0xffff0000u);
        hi.w = (r[6] >> 16) | (r[7] & 0xffff0000u);
        *(uint4*)(pbase + (size_t)l * 8) = lo;       // row l
        *(uint4*)(pbase + (size_t)l * 8 + 8) = hi;   // row l+1
    }
}

// ---------------- LDS-free MFMA GEMM: out[b] = W @ G[b] + bias ----------------
// A-frags from Wp[k/8][m][8], B-frags from gP[b][k/8][l][8]; 4 indep waves/block.
__global__ __launch_bounds__(256) void s4_gemm_mfma(
        const ushort* __restrict__ gP, const ushort* __restrict__ Wp,
        const float* __restrict__ bias, float* __restrict__ out) {
    const int tid = threadIdx.x;
    const int wv = tid >> 6, lane = tid & 63;
    const int l15 = lane & 15, lg = lane >> 4;
    const int b = blockIdx.z;
    const int m0 = blockIdx.y << 6;                       // 64 h' rows per block
    const int l0 = ((blockIdx.x << 2) | wv) << 6;         // 64 l cols per wave
    f32x4 acc[4][4] = {};
    const ushort* wpl = Wp + (size_t)(m0 + l15) * 8;
    const ushort* gpl = gP + ((size_t)(b * 32) * S4_L + l0 + l15) * 8;
    for (int kb = 0; kb < 8; ++kb) {
        const int ko = kb * 4 + lg;                       // k-octet: k = ko*8..ko*8+7
        bf16x8 aF[4], bF[4];
        #pragma unroll
        for (int i = 0; i < 4; ++i)
            aF[i] = *(const bf16x8*)(wpl + ((size_t)ko * S4_H + i * 16) * 8);
        #pragma unroll
        for (int j = 0; j < 4; ++j)
            bF[j] = *(const bf16x8*)(gpl + ((size_t)ko * S4_L + j * 16) * 8);
        #pragma unroll
        for (int i = 0; i < 4; ++i)
            #pragma unroll
            for (int j = 0; j < 4; ++j)
                acc[i][j] = __builtin_amdgcn_mfma_f32_16x16x32_bf16(aF[i], bF[j], acc[i][j], 0, 0, 0);
    }
    float* ob = out + (size_t)b * S4_H * S4_L;
    #pragma unroll
    for (int i = 0; i < 4; ++i) {
        #pragma unroll
        for (int jj = 0; jj < 4; ++jj) {
            const int row = m0 + i * 16 + lg * 4 + jj;
            const float bv = bias[row];
            float* orow = ob + (size_t)row * S4_L + l0 + l15;
            #pragma unroll
            for (int j = 0; j < 4; ++j)
                orow[j * 16] = acc[i][j][jj] + bv;
        }
    }
}

extern "C" void kernel_launch(void* const* d_in, const int* in_sizes, int n_in,
                              void* d_out, int out_size, void* d_ws, size_t ws_size,
                              hipStream_t stream) {
    const float* inp        = (const float*)d_in[0]; // (B,CIN,F,L) == (B,H,L)
    const float* log_dt     = (const float*)d_in[1];
    const float* log_A_real = (const float*)d_in[2];
    const float* A_imag     = (const float*)d_in[3];
    const float* C_real     = (const float*)d_in[4];
    const float* C_imag     = (const float*)d_in[5];
    const float* D          = (const float*)d_in[6];
    const float* W_out      = (const float*)d_in[7];
    const float* b_out      = (const float*)d_in[8];
    float* out = (float*)d_out;

    char* wsc = (char*)d_ws;
    size_t off = 0;
    float* wT     = (float*)(wsc + off);  off += (64 << 10);       // 64 KB
    ushort* Ebf   = (ushort*)(wsc + off); off += (2 << 20);        // 2 MB
    ushort* TMbf  = (ushort*)(wsc + off); off += (2 << 20);        // 2 MB
    ushort* Vbf   = (ushort*)(wsc + off); off += (2 << 20);        // 2 MB
    ushort* Wp    = (ushort*)(wsc + off); off += (128 << 10);      // 128 KB
    uint32_t* g   = (uint32_t*)(wsc + off); off += (size_t)S4_B * S4_H * S4_L * 2; // 33.5 MB
    ushort* gP    = (ushort*)(wsc + off);                           // 33.5 MB

    hipLaunchKernelGGL(s4_tab_kernel, dim3(S4_H), dim3(64), 0, stream,
                       log_dt, log_A_real, A_imag, C_real, C_imag, wT, Ebf, TMbf, Vbf);
    hipLaunchKernelGGL(s4_wconv, dim3(32), dim3(256), 0, stream, W_out, Wp);
    hipLaunchKernelGGL(s4_scan_fused, dim3(S4_B * S4_H), dim3(256), 0, stream,
                       inp, wT, Ebf, TMbf, Vbf, D, g);
    hipLaunchKernelGGL(s4_g2p, dim3(32, S4_B), dim3(256), 0, stream,
                       (const ushort*)g, gP);
    hipLaunchKernelGGL(s4_gemm_mfma, dim3(S4_L / 256, S4_H / 64, S4_B), dim3(256), 0, stream,
                       gP, Wp, b_out, out);
}

// Round 4
// 88.072 us; speedup vs baseline: 5.2184x; 1.0277x over previous
//
#include <hip/hip_runtime.h>
#include <hip/hip_bf16.h>
#include <cstdint>

#define S4_H 256
#define S4_N 32
#define S4_L 4096
#define S4_B 16
#define S4_T 64
#define S4_C 64

typedef __attribute__((ext_vector_type(8))) short bf16x8;
typedef __attribute__((ext_vector_type(4))) float f32x4;

// round-to-nearest-even f32 -> bf16 (finite inputs)
__device__ __forceinline__ uint32_t s4_f2bf(float f) {
    uint32_t u = __float_as_uint(f);
    return (u + 0x7fffu + ((u >> 16) & 1u)) >> 16;
}

// tanh-approx GELU: x * sigmoid(1.59577*(x + 0.044715 x^3))
__device__ __forceinline__ float s4_gelu(float x) {
    float x3 = x * x * x;
    float z = 1.5957691216057308f * fmaf(0.044715f, x3, x);
    float e = __expf(-z);
    return x / (1.0f + e);
}

// sum within each 32-lane half via DPP; result valid in lanes 31 and 63
__device__ __forceinline__ float s4_rowsum32(float v) {
    v += __int_as_float(__builtin_amdgcn_update_dpp(0, __float_as_int(v), 0x111, 0xf, 0xf, false)); // row_shr:1
    v += __int_as_float(__builtin_amdgcn_update_dpp(0, __float_as_int(v), 0x112, 0xf, 0xf, false)); // row_shr:2
    v += __int_as_float(__builtin_amdgcn_update_dpp(0, __float_as_int(v), 0x114, 0xf, 0xf, false)); // row_shr:4
    v += __int_as_float(__builtin_amdgcn_update_dpp(0, __float_as_int(v), 0x118, 0xf, 0xf, false)); // row_shr:8
    v += __int_as_float(__builtin_amdgcn_update_dpp(0, __float_as_int(v), 0x142, 0xf, 0xf, false)); // row_bcast15
    return v;
}

// ---------------- table kernel: per-h E, Toeplitz(K), V tables (bf16) + w^T ----------------
__global__ __launch_bounds__(64) void s4_tab_kernel(
        const float* __restrict__ log_dt, const float* __restrict__ log_A_real,
        const float* __restrict__ A_imag, const float* __restrict__ C_real,
        const float* __restrict__ C_imag,
        float* __restrict__ wT, ushort* __restrict__ Ebf,
        ushort* __restrict__ TMbf, ushort* __restrict__ Vbf) {
    const int h = blockIdx.x, tid = threadIdx.x, n = tid & 31;
    __shared__ float Ksh[S4_T];
    const int idx = h * 32 + n;
    float dt = expf(log_dt[h]);
    float Ar = -expf(log_A_real[idx]);
    float Ai = A_imag[idx];
    float er = expf(dt * Ar);
    float wr = er * cosf(dt * Ai);
    float wi = er * sinf(dt * Ai);
    float inv = 1.0f / (Ar * Ar + Ai * Ai);
    float mr = wr - 1.0f, mi = wi;
    float qr = (mr * Ar + mi * Ai) * inv;
    float qi = (mi * Ar - mr * Ai) * inv;
    float Cr = C_real[idx], Ci = C_imag[idx];
    float cr = 2.0f * (Cr * qr - Ci * qi);    //  2*Re(Chat)
    float ci = -2.0f * (Cr * qi + Ci * qr);   // -2*Im(Chat)
    ushort* Eh = Ebf + h * 4096;
    ushort* Vh = Vbf + h * 4096;
    float pr = 1.0f, pi = 0.0f;               // p = w^t
    for (int t = 0; t < S4_T; ++t) {
        if (tid < 32) {
            Eh[(2 * n) * 64 + (63 - t)]     = (ushort)s4_f2bf(pr);
            Eh[(2 * n + 1) * 64 + (63 - t)] = (ushort)s4_f2bf(pi);
        }
        float kt = s4_rowsum32(fmaf(cr, pr, ci * pi));   // K[t] = 2Re(sum Chat w^t)
        if (tid == 31) Ksh[t] = kt;
        float Qr = pr * wr - pi * wi;          // Q = w^{t+1}
        float Qi = pr * wi + pi * wr;
        if (tid < 32) {
            Vh[t * 64 + 2 * n]     = (ushort)s4_f2bf(fmaf(cr, Qr, ci * Qi));   //  2Re(Chat Q)
            Vh[t * 64 + 2 * n + 1] = (ushort)s4_f2bf(fmaf(ci, Qr, -cr * Qi));  // -2Im(Chat Q)
        }
        pr = Qr; pi = Qi;
    }
    if (tid < 32) { wT[idx] = pr; wT[8192 + idx] = pi; }   // w^64
    __syncthreads();
    ushort* TMh = TMbf + h * 4096;
    for (int e = tid; e < 4096; e += 64) {
        int to = e >> 6, ti = e & 63;
        TMh[e] = (ti <= to) ? (ushort)s4_f2bf(Ksh[to - ti]) : (ushort)0;
    }
}

// ---------------- W f32 -> octet-interleaved bf16: Wp[k/8][m][8] ----------------
__global__ __launch_bounds__(256) void s4_wconv(const float* __restrict__ W,
                                               ushort* __restrict__ Wp) {
    const int m = threadIdx.x, ko = blockIdx.x;
    const float* src = W + (size_t)m * S4_H + ko * 8;
    float4 a = *(const float4*)src;
    float4 b = *(const float4*)(src + 4);
    uint4 pk;
    pk.x = s4_f2bf(a.x) | (s4_f2bf(a.y) << 16);
    pk.y = s4_f2bf(a.z) | (s4_f2bf(a.w) << 16);
    pk.z = s4_f2bf(b.x) | (s4_f2bf(b.y) << 16);
    pk.w = s4_f2bf(b.z) | (s4_f2bf(b.w) << 16);
    *(uint4*)(Wp + ((size_t)ko * S4_H + m) * 8) = pk;
}

// ---------------- fused chunk-parallel scan: one block per (b,h) ----------------
// LDS: Ubuf (u bf16) reused for X after phase 1; Ssh padded [64][66] (conflict-free).
__global__ __launch_bounds__(256) void s4_scan_fused(
        const float* __restrict__ u, const float* __restrict__ wT,
        const ushort* __restrict__ Ebf, const ushort* __restrict__ TMbf,
        const ushort* __restrict__ Vbf, const float* __restrict__ D,
        uint32_t* __restrict__ g) {
    __shared__ char UXbfB[8192];       // u as bf16 in phase1; X states in phase2/3
    __shared__ float Ssh[64][66];      // [c][r] chunk sums, padded rows (264B stride)
    const int tid = threadIdx.x;
    const int bh = blockIdx.x;
    const int h = bh & (S4_H - 1);
    const int w = tid >> 6, lane = tid & 63;
    const int l15 = lane & 15, lg = lane >> 4;

    // ---- stage U: 16 f32 per thread -> bf16 LDS ----
    const float* up = u + (size_t)bh * S4_L;
    {
        const float4* uf = (const float4*)(up) + tid * 4;
        #pragma unroll
        for (int j = 0; j < 4; ++j) {
            float4 v = uf[j];
            uint2 pk;
            pk.x = s4_f2bf(v.x) | (s4_f2bf(v.y) << 16);
            pk.y = s4_f2bf(v.z) | (s4_f2bf(v.w) << 16);
            int o = tid * 32 + j * 8;
            *(uint2*)(UXbfB + (o ^ (((o >> 7) & 7) << 4))) = pk;
        }
    }
    // ---- A-fragments (row = 16w + l15, k0 = lg*8) straight from global (L2-hot) ----
    const int arow = 16 * w + l15;
    const size_t tb = (size_t)h * 4096 + (size_t)arow * 64 + lg * 8;
    bf16x8 eA0 = *(const bf16x8*)(Ebf + tb);
    bf16x8 eA1 = *(const bf16x8*)(Ebf + tb + 32);
    bf16x8 tA0 = *(const bf16x8*)(TMbf + tb);
    bf16x8 tA1 = *(const bf16x8*)(TMbf + tb + 32);
    bf16x8 vA0 = *(const bf16x8*)(Vbf + tb);
    bf16x8 vA1 = *(const bf16x8*)(Vbf + tb + 32);
    __syncthreads();

    // ---- phase 1: S = E @ U; also pull epilogue-u values into regs ----
    bf16x8 ufr[4][2];
    uint2 eu[4];
    const int t0 = 16 * w + lg * 4;
    #pragma unroll
    for (int ct = 0; ct < 4; ++ct) {
        int c = ct * 16 + l15;
        int swz = (c & 7) << 4;
        ufr[ct][0] = *(const bf16x8*)(UXbfB + c * 128 + ((lg * 16) ^ swz));
        ufr[ct][1] = *(const bf16x8*)(UXbfB + c * 128 + ((64 + lg * 16) ^ swz));
        eu[ct] = *(const uint2*)(UXbfB + c * 128 + ((t0 * 2) ^ swz));
        f32x4 acc = {0.f, 0.f, 0.f, 0.f};
        acc = __builtin_amdgcn_mfma_f32_16x16x32_bf16(eA0, ufr[ct][0], acc, 0, 0, 0);
        acc = __builtin_amdgcn_mfma_f32_16x16x32_bf16(eA1, ufr[ct][1], acc, 0, 0, 0);
        *(f32x4*)(&Ssh[c][16 * w + lg * 4]) = acc;   // rows r = 16w + lg*4 + j
    }
    __syncthreads();   // all U reads done -> UXbfB reusable for X

    // ---- phase 2: X[c] = state before chunk c; x <- wT*x + S[c] ----
    if (tid < 32) {
        float wtr = wT[h * 32 + tid], wti = wT[8192 + h * 32 + tid];
        float xr = 0.f, xi = 0.f;
        #pragma unroll 4
        for (int c = 0; c < S4_C; ++c) {
            int o = c * 128 + tid * 4;
            *(uint32_t*)(UXbfB + (o ^ (((c & 7) << 4)))) = s4_f2bf(xr) | (s4_f2bf(xi) << 16);
            float2 s2 = *(const float2*)(&Ssh[c][2 * tid]);
            float nr2 = fmaf(wtr, xr, fmaf(-wti, xi, s2.x));
            float ni2 = fmaf(wtr, xi, fmaf(wti, xr, s2.y));
            xr = nr2; xi = ni2;
        }
    }
    __syncthreads();

    // ---- phase 3: Y = TM@U + V@X, fused epilogue ----
    const float Dh = D[h];
    uint32_t* gp = g + (size_t)bh * (S4_L / 2);
    #pragma unroll
    for (int ct = 0; ct < 4; ++ct) {
        int c = ct * 16 + l15;
        int swz = (c & 7) << 4;
        bf16x8 xb0 = *(const bf16x8*)(UXbfB + c * 128 + ((lg * 16) ^ swz));
        bf16x8 xb1 = *(const bf16x8*)(UXbfB + c * 128 + ((64 + lg * 16) ^ swz));
        f32x4 y = {0.f, 0.f, 0.f, 0.f};
        y = __builtin_amdgcn_mfma_f32_16x16x32_bf16(tA0, ufr[ct][0], y, 0, 0, 0);
        if (w >= 2)   // Toeplitz rows < 32 have zero k>=32 block: skip the all-zero MFMA
            y = __builtin_amdgcn_mfma_f32_16x16x32_bf16(tA1, ufr[ct][1], y, 0, 0, 0);
        y = __builtin_amdgcn_mfma_f32_16x16x32_bf16(vA0, xb0, y, 0, 0, 0);
        y = __builtin_amdgcn_mfma_f32_16x16x32_bf16(vA1, xb1, y, 0, 0, 0);
        uint2 upk = eu[ct];
        float u0 = __uint_as_float(upk.x << 16);
        float u1 = __uint_as_float(upk.x & 0xffff0000u);
        float u2 = __uint_as_float(upk.y << 16);
        float u3 = __uint_as_float(upk.y & 0xffff0000u);
        float g0 = s4_gelu(fmaf(Dh, u0, y[0]));
        float g1 = s4_gelu(fmaf(Dh, u1, y[1]));
        float g2 = s4_gelu(fmaf(Dh, u2, y[2]));
        float g3 = s4_gelu(fmaf(Dh, u3, y[3]));
        uint2 opk;
        opk.x = s4_f2bf(g0) | (s4_f2bf(g1) << 16);
        opk.y = s4_f2bf(g2) | (s4_f2bf(g3) << 16);
        *(uint2*)(gp + (c * 64 + t0) / 2) = opk;
    }
}

// ---------------- octet transpose: g (B,H,L) -> gP[b][h/8][l][8] (all bf16) ----------------
__global__ __launch_bounds__(256) void s4_g2p(const ushort* __restrict__ g,
                                              ushort* __restrict__ gP) {
    const int ho = blockIdx.x, b = blockIdx.y;
    const int t = threadIdx.x;
    const ushort* gbase = g + (size_t)(b * S4_H + ho * 8) * S4_L;
    ushort* pbase = gP + (size_t)(b * 32 + ho) * S4_L * 8;
    for (int it = 0; it < 8; ++it) {
        int l = it * 512 + t * 2;
        uint32_t r[8];
        #pragma unroll
        for (int i = 0; i < 8; ++i)
            r[i] = *(const uint32_t*)(gbase + (size_t)i * S4_L + l);
        uint4 lo, hi;
        lo.x = (r[0] & 0xffffu) | (r[1] << 16);
        lo.y = (r[2] & 0xffffu) | (r[3] << 16);
        lo.z = (r[4] & 0xffffu) | (r[5] << 16);
        lo.w = (r[6] & 0xffffu) | (r[7] << 16);
        hi.x = (r[0] >> 16) | (r[1] & 0xffff0000u);
        hi.y = (r[2] >> 16) | (r[3] & 0xffff0000u);
        hi.z = (r[4] >> 16) | (r[5] & 0xffff0000u);
        hi.w = (r[6] >> 16) | (r[7] & 0xffff0000u);
        *(uint4*)(pbase + (size_t)l * 8) = lo;       // row l
        *(uint4*)(pbase + (size_t)l * 8 + 8) = hi;   // row l+1
    }
}

// ---------------- LDS-free MFMA GEMM: out[b] = W @ G[b] + bias ----------------
// A-frags from Wp[k/8][m][8], B-frags from gP[b][k/8][l][8]; 4 indep waves/block.
__global__ __launch_bounds__(256) void s4_gemm_mfma(
        const ushort* __restrict__ gP, const ushort* __restrict__ Wp,
        const float* __restrict__ bias, float* __restrict__ out) {
    const int tid = threadIdx.x;
    const int wv = tid >> 6, lane = tid & 63;
    const int l15 = lane & 15, lg = lane >> 4;
    const int b = blockIdx.z;
    const int m0 = blockIdx.y << 6;                       // 64 h' rows per block
    const int l0 = ((blockIdx.x << 2) | wv) << 6;         // 64 l cols per wave
    f32x4 acc[4][4] = {};
    const ushort* wpl = Wp + (size_t)(m0 + l15) * 8;
    const ushort* gpl = gP + ((size_t)(b * 32) * S4_L + l0 + l15) * 8;
    for (int kb = 0; kb < 8; ++kb) {
        const int ko = kb * 4 + lg;                       // k-octet: k = ko*8..ko*8+7
        bf16x8 aF[4], bF[4];
        #pragma unroll
        for (int i = 0; i < 4; ++i)
            aF[i] = *(const bf16x8*)(wpl + ((size_t)ko * S4_H + i * 16) * 8);
        #pragma unroll
        for (int j = 0; j < 4; ++j)
            bF[j] = *(const bf16x8*)(gpl + ((size_t)ko * S4_L + j * 16) * 8);
        #pragma unroll
        for (int i = 0; i < 4; ++i)
            #pragma unroll
            for (int j = 0; j < 4; ++j)
                acc[i][j] = __builtin_amdgcn_mfma_f32_16x16x32_bf16(aF[i], bF[j], acc[i][j], 0, 0, 0);
    }
    float* ob = out + (size_t)b * S4_H * S4_L;
    #pragma unroll
    for (int i = 0; i < 4; ++i) {
        #pragma unroll
        for (int jj = 0; jj < 4; ++jj) {
            const int row = m0 + i * 16 + lg * 4 + jj;
            const float bv = bias[row];
            float* orow = ob + (size_t)row * S4_L + l0 + l15;
            #pragma unroll
            for (int j = 0; j < 4; ++j)
                orow[j * 16] = acc[i][j][jj] + bv;
        }
    }
}

extern "C" void kernel_launch(void* const* d_in, const int* in_sizes, int n_in,
                              void* d_out, int out_size, void* d_ws, size_t ws_size,
                              hipStream_t stream) {
    const float* inp        = (const float*)d_in[0]; // (B,CIN,F,L) == (B,H,L)
    const float* log_dt     = (const float*)d_in[1];
    const float* log_A_real = (const float*)d_in[2];
    const float* A_imag     = (const float*)d_in[3];
    const float* C_real     = (const float*)d_in[4];
    const float* C_imag     = (const float*)d_in[5];
    const float* D          = (const float*)d_in[6];
    const float* W_out      = (const float*)d_in[7];
    const float* b_out      = (const float*)d_in[8];
    float* out = (float*)d_out;

    char* wsc = (char*)d_ws;
    size_t off = 0;
    float* wT     = (float*)(wsc + off);  off += (64 << 10);       // 64 KB
    ushort* Ebf   = (ushort*)(wsc + off); off += (2 << 20);        // 2 MB
    ushort* TMbf  = (ushort*)(wsc + off); off += (2 << 20);        // 2 MB
    ushort* Vbf   = (ushort*)(wsc + off); off += (2 << 20);        // 2 MB
    ushort* Wp    = (ushort*)(wsc + off); off += (128 << 10);      // 128 KB
    uint32_t* g   = (uint32_t*)(wsc + off); off += (size_t)S4_B * S4_H * S4_L * 2; // 33.5 MB
    ushort* gP    = (ushort*)(wsc + off);                           // 33.5 MB

    hipLaunchKernelGGL(s4_tab_kernel, dim3(S4_H), dim3(64), 0, stream,
                       log_dt, log_A_real, A_imag, C_real, C_imag, wT, Ebf, TMbf, Vbf);
    hipLaunchKernelGGL(s4_wconv, dim3(32), dim3(256), 0, stream, W_out, Wp);
    hipLaunchKernelGGL(s4_scan_fused, dim3(S4_B * S4_H), dim3(256), 0, stream,
                       inp, wT, Ebf, TMbf, Vbf, D, g);
    hipLaunchKernelGGL(s4_g2p, dim3(32, S4_B), dim3(256), 0, stream,
                       (const ushort*)g, gP);
    hipLaunchKernelGGL(s4_gemm_mfma, dim3(S4_L / 256, S4_H / 64, S4_B), dim3(256), 0, stream,
                       gP, Wp, b_out, out);
}

// Round 5
// 85.432 us; speedup vs baseline: 5.3797x; 1.0309x over previous
//
#include <hip/hip_runtime.h>
#include <hip/hip_bf16.h>
#include <cstdint>

#define S4_H 256
#define S4_N 32
#define S4_L 4096
#define S4_B 16
#define S4_T 64
#define S4_C 64

typedef __attribute__((ext_vector_type(8))) short bf16x8;
typedef __attribute__((ext_vector_type(4))) float f32x4;

// round-to-nearest-even f32 -> bf16 (finite inputs)
__device__ __forceinline__ uint32_t s4_f2bf(float f) {
    uint32_t u = __float_as_uint(f);
    return (u + 0x7fffu + ((u >> 16) & 1u)) >> 16;
}

// tanh-approx GELU: x * sigmoid(1.59577*(x + 0.044715 x^3))
__device__ __forceinline__ float s4_gelu(float x) {
    float x3 = x * x * x;
    float z = 1.5957691216057308f * fmaf(0.044715f, x3, x);
    float e = __expf(-z);
    return x / (1.0f + e);
}

// sum within each 32-lane half via DPP; result valid in lanes 31 and 63
__device__ __forceinline__ float s4_rowsum32(float v) {
    v += __int_as_float(__builtin_amdgcn_update_dpp(0, __float_as_int(v), 0x111, 0xf, 0xf, false)); // row_shr:1
    v += __int_as_float(__builtin_amdgcn_update_dpp(0, __float_as_int(v), 0x112, 0xf, 0xf, false)); // row_shr:2
    v += __int_as_float(__builtin_amdgcn_update_dpp(0, __float_as_int(v), 0x114, 0xf, 0xf, false)); // row_shr:4
    v += __int_as_float(__builtin_amdgcn_update_dpp(0, __float_as_int(v), 0x118, 0xf, 0xf, false)); // row_shr:8
    v += __int_as_float(__builtin_amdgcn_update_dpp(0, __float_as_int(v), 0x142, 0xf, 0xf, false)); // row_bcast15
    return v;
}

// ---------------- table kernel: per-h E, Toeplitz(K), V tables (bf16) + w^T ----------------
__global__ __launch_bounds__(64) void s4_tab_kernel(
        const float* __restrict__ log_dt, const float* __restrict__ log_A_real,
        const float* __restrict__ A_imag, const float* __restrict__ C_real,
        const float* __restrict__ C_imag,
        float* __restrict__ wT, ushort* __restrict__ Ebf,
        ushort* __restrict__ TMbf, ushort* __restrict__ Vbf) {
    const int h = blockIdx.x, tid = threadIdx.x, n = tid & 31;
    __shared__ float Ksh[S4_T];
    const int idx = h * 32 + n;
    float dt = expf(log_dt[h]);
    float Ar = -expf(log_A_real[idx]);
    float Ai = A_imag[idx];
    float er = expf(dt * Ar);
    float wr = er * cosf(dt * Ai);
    float wi = er * sinf(dt * Ai);
    float inv = 1.0f / (Ar * Ar + Ai * Ai);
    float mr = wr - 1.0f, mi = wi;
    float qr = (mr * Ar + mi * Ai) * inv;
    float qi = (mi * Ar - mr * Ai) * inv;
    float Cr = C_real[idx], Ci = C_imag[idx];
    float cr = 2.0f * (Cr * qr - Ci * qi);    //  2*Re(Chat)
    float ci = -2.0f * (Cr * qi + Ci * qr);   // -2*Im(Chat)
    ushort* Eh = Ebf + h * 4096;
    ushort* Vh = Vbf + h * 4096;
    float pr = 1.0f, pi = 0.0f;               // p = w^t
    for (int t = 0; t < S4_T; ++t) {
        if (tid < 32) {
            Eh[(2 * n) * 64 + (63 - t)]     = (ushort)s4_f2bf(pr);
            Eh[(2 * n + 1) * 64 + (63 - t)] = (ushort)s4_f2bf(pi);
        }
        float kt = s4_rowsum32(fmaf(cr, pr, ci * pi));   // K[t] = 2Re(sum Chat w^t)
        if (tid == 31) Ksh[t] = kt;
        float Qr = pr * wr - pi * wi;          // Q = w^{t+1}
        float Qi = pr * wi + pi * wr;
        if (tid < 32) {
            Vh[t * 64 + 2 * n]     = (ushort)s4_f2bf(fmaf(cr, Qr, ci * Qi));   //  2Re(Chat Q)
            Vh[t * 64 + 2 * n + 1] = (ushort)s4_f2bf(fmaf(ci, Qr, -cr * Qi));  // -2Im(Chat Q)
        }
        pr = Qr; pi = Qi;
    }
    if (tid < 32) { wT[idx] = pr; wT[8192 + idx] = pi; }   // w^64
    __syncthreads();
    ushort* TMh = TMbf + h * 4096;
    for (int e = tid; e < 4096; e += 64) {
        int to = e >> 6, ti = e & 63;
        TMh[e] = (ti <= to) ? (ushort)s4_f2bf(Ksh[to - ti]) : (ushort)0;
    }
}

// ---------------- W f32 -> octet-interleaved bf16: Wp[k/8][m][8] ----------------
__global__ __launch_bounds__(256) void s4_wconv(const float* __restrict__ W,
                                               ushort* __restrict__ Wp) {
    const int m = threadIdx.x, ko = blockIdx.x;
    const float* src = W + (size_t)m * S4_H + ko * 8;
    float4 a = *(const float4*)src;
    float4 b = *(const float4*)(src + 4);
    uint4 pk;
    pk.x = s4_f2bf(a.x) | (s4_f2bf(a.y) << 16);
    pk.y = s4_f2bf(a.z) | (s4_f2bf(a.w) << 16);
    pk.z = s4_f2bf(b.x) | (s4_f2bf(b.y) << 16);
    pk.w = s4_f2bf(b.z) | (s4_f2bf(b.w) << 16);
    *(uint4*)(Wp + ((size_t)ko * S4_H + m) * 8) = pk;
}

// ---------------- fused chunk-parallel scan: one block per (b,h) ----------------
// Phase2 fully unrolled (software-pipelined S-loads); TM@U overlapped with phase2.
__global__ __launch_bounds__(256, 6) void s4_scan_fused(
        const float* __restrict__ u, const float* __restrict__ wT,
        const ushort* __restrict__ Ebf, const ushort* __restrict__ TMbf,
        const ushort* __restrict__ Vbf, const float* __restrict__ D,
        uint32_t* __restrict__ g) {
    __shared__ char UXbfB[8192];       // u as bf16 in phase1; X states in phase2/3
    __shared__ float Ssh[64][66];      // [c][r] chunk sums, padded rows (264B stride)
    const int tid = threadIdx.x;
    const int bh = blockIdx.x;
    const int h = bh & (S4_H - 1);
    const int w = tid >> 6, lane = tid & 63;
    const int l15 = lane & 15, lg = lane >> 4;

    // ---- stage U: 16 f32 per thread -> bf16 LDS ----
    const float* up = u + (size_t)bh * S4_L;
    {
        const float4* uf = (const float4*)(up) + tid * 4;
        #pragma unroll
        for (int j = 0; j < 4; ++j) {
            float4 v = uf[j];
            uint2 pk;
            pk.x = s4_f2bf(v.x) | (s4_f2bf(v.y) << 16);
            pk.y = s4_f2bf(v.z) | (s4_f2bf(v.w) << 16);
            int o = tid * 32 + j * 8;
            *(uint2*)(UXbfB + (o ^ (((o >> 7) & 7) << 4))) = pk;
        }
    }
    // ---- A-fragments (row = 16w + l15, k0 = lg*8) straight from global (L2-hot) ----
    const int arow = 16 * w + l15;
    const size_t tb = (size_t)h * 4096 + (size_t)arow * 64 + lg * 8;
    bf16x8 eA0 = *(const bf16x8*)(Ebf + tb);
    bf16x8 eA1 = *(const bf16x8*)(Ebf + tb + 32);
    bf16x8 tA0 = *(const bf16x8*)(TMbf + tb);
    bf16x8 tA1 = *(const bf16x8*)(TMbf + tb + 32);
    bf16x8 vA0 = *(const bf16x8*)(Vbf + tb);
    bf16x8 vA1 = *(const bf16x8*)(Vbf + tb + 32);
    __syncthreads();

    // ---- phase 1: S = E @ U; also pull epilogue-u values into regs ----
    bf16x8 ufr[4][2];
    uint2 eu[4];
    const int t0 = 16 * w + lg * 4;
    #pragma unroll
    for (int ct = 0; ct < 4; ++ct) {
        int c = ct * 16 + l15;
        int swz = (c & 7) << 4;
        ufr[ct][0] = *(const bf16x8*)(UXbfB + c * 128 + ((lg * 16) ^ swz));
        ufr[ct][1] = *(const bf16x8*)(UXbfB + c * 128 + ((64 + lg * 16) ^ swz));
        eu[ct] = *(const uint2*)(UXbfB + c * 128 + ((t0 * 2) ^ swz));
        f32x4 acc = {0.f, 0.f, 0.f, 0.f};
        acc = __builtin_amdgcn_mfma_f32_16x16x32_bf16(eA0, ufr[ct][0], acc, 0, 0, 0);
        acc = __builtin_amdgcn_mfma_f32_16x16x32_bf16(eA1, ufr[ct][1], acc, 0, 0, 0);
        *(f32x4*)(&Ssh[c][16 * w + lg * 4]) = acc;   // rows r = 16w + lg*4 + j
    }
    __syncthreads();   // all U reads done -> UXbfB reusable for X

    // ---- phase 3a: Y = TM@U (X-independent) — overlaps with wave0's phase 2 ----
    f32x4 yac[4];
    #pragma unroll
    for (int ct = 0; ct < 4; ++ct) {
        f32x4 y = {0.f, 0.f, 0.f, 0.f};
        y = __builtin_amdgcn_mfma_f32_16x16x32_bf16(tA0, ufr[ct][0], y, 0, 0, 0);
        if (w >= 2)   // Toeplitz rows < 32 have zero k>=32 block: skip the all-zero MFMA
            y = __builtin_amdgcn_mfma_f32_16x16x32_bf16(tA1, ufr[ct][1], y, 0, 0, 0);
        yac[ct] = y;
    }

    // ---- phase 2 (wave 0): X[c] = state before chunk c; x <- wT*x + S[c] ----
    // Fully unrolled: all 64 ds_read addresses static & x-independent -> pipelined.
    if (tid < 32) {
        float wtr = wT[h * 32 + tid], wti = wT[8192 + h * 32 + tid];
        float xr = 0.f, xi = 0.f;
        #pragma unroll
        for (int c = 0; c < S4_C; ++c) {
            int o = c * 128 + tid * 4;
            *(uint32_t*)(UXbfB + (o ^ (((c & 7) << 4)))) = s4_f2bf(xr) | (s4_f2bf(xi) << 16);
            float2 s2 = *(const float2*)(&Ssh[c][2 * tid]);
            float nr2 = fmaf(wtr, xr, fmaf(-wti, xi, s2.x));
            float ni2 = fmaf(wtr, xi, fmaf(wti, xr, s2.y));
            xr = nr2; xi = ni2;
        }
    }
    __syncthreads();

    // ---- phase 3b: Y += V@X, fused epilogue ----
    const float Dh = D[h];
    uint32_t* gp = g + (size_t)bh * (S4_L / 2);
    #pragma unroll
    for (int ct = 0; ct < 4; ++ct) {
        int c = ct * 16 + l15;
        int swz = (c & 7) << 4;
        bf16x8 xb0 = *(const bf16x8*)(UXbfB + c * 128 + ((lg * 16) ^ swz));
        bf16x8 xb1 = *(const bf16x8*)(UXbfB + c * 128 + ((64 + lg * 16) ^ swz));
        f32x4 y = yac[ct];
        y = __builtin_amdgcn_mfma_f32_16x16x32_bf16(vA0, xb0, y, 0, 0, 0);
        y = __builtin_amdgcn_mfma_f32_16x16x32_bf16(vA1, xb1, y, 0, 0, 0);
        uint2 upk = eu[ct];
        float u0 = __uint_as_float(upk.x << 16);
        float u1 = __uint_as_float(upk.x & 0xffff0000u);
        float u2 = __uint_as_float(upk.y << 16);
        float u3 = __uint_as_float(upk.y & 0xffff0000u);
        float g0 = s4_gelu(fmaf(Dh, u0, y[0]));
        float g1 = s4_gelu(fmaf(Dh, u1, y[1]));
        float g2 = s4_gelu(fmaf(Dh, u2, y[2]));
        float g3 = s4_gelu(fmaf(Dh, u3, y[3]));
        uint2 opk;
        opk.x = s4_f2bf(g0) | (s4_f2bf(g1) << 16);
        opk.y = s4_f2bf(g2) | (s4_f2bf(g3) << 16);
        *(uint2*)(gp + (c * 64 + t0) / 2) = opk;
    }
}

// ---------------- octet transpose: g (B,H,L) -> gP[b][h/8][l][8] (all bf16) ----------------
__global__ __launch_bounds__(256) void s4_g2p(const ushort* __restrict__ g,
                                              ushort* __restrict__ gP) {
    const int ho = blockIdx.x, b = blockIdx.y;
    const int t = threadIdx.x;
    const ushort* gbase = g + (size_t)(b * S4_H + ho * 8) * S4_L;
    ushort* pbase = gP + (size_t)(b * 32 + ho) * S4_L * 8;
    for (int it = 0; it < 8; ++it) {
        int l = it * 512 + t * 2;
        uint32_t r[8];
        #pragma unroll
        for (int i = 0; i < 8; ++i)
            r[i] = *(const uint32_t*)(gbase + (size_t)i * S4_L + l);
        uint4 lo, hi;
        lo.x = (r[0] & 0xffffu) | (r[1] << 16);
        lo.y = (r[2] & 0xffffu) | (r[3] << 16);
        lo.z = (r[4] & 0xffffu) | (r[5] << 16);
        lo.w = (r[6] & 0xffffu) | (r[7] << 16);
        hi.x = (r[0] >> 16) | (r[1] & 0xffff0000u);
        hi.y = (r[2] >> 16) | (r[3] & 0xffff0000u);
        hi.z = (r[4] >> 16) | (r[5] & 0xffff0000u);
        hi.w = (r[6] >> 16) | (r[7] & 0xffff0000u);
        *(uint4*)(pbase + (size_t)l * 8) = lo;       // row l
        *(uint4*)(pbase + (size_t)l * 8 + 8) = hi;   // row l+1
    }
}

// ---------------- LDS-free MFMA GEMM: out[b] = W @ G[b] + bias ----------------
// A-frags from Wp[k/8][m][8], B-frags from gP[b][k/8][l][8]; 4 indep waves/block.
__global__ __launch_bounds__(256) void s4_gemm_mfma(
        const ushort* __restrict__ gP, const ushort* __restrict__ Wp,
        const float* __restrict__ bias, float* __restrict__ out) {
    const int tid = threadIdx.x;
    const int wv = tid >> 6, lane = tid & 63;
    const int l15 = lane & 15, lg = lane >> 4;
    const int b = blockIdx.z;
    const int m0 = blockIdx.y << 6;                       // 64 h' rows per block
    const int l0 = ((blockIdx.x << 2) | wv) << 6;         // 64 l cols per wave
    f32x4 acc[4][4] = {};
    const ushort* wpl = Wp + (size_t)(m0 + l15) * 8;
    const ushort* gpl = gP + ((size_t)(b * 32) * S4_L + l0 + l15) * 8;
    for (int kb = 0; kb < 8; ++kb) {
        const int ko = kb * 4 + lg;                       // k-octet: k = ko*8..ko*8+7
        bf16x8 aF[4], bF[4];
        #pragma unroll
        for (int i = 0; i < 4; ++i)
            aF[i] = *(const bf16x8*)(wpl + ((size_t)ko * S4_H + i * 16) * 8);
        #pragma unroll
        for (int j = 0; j < 4; ++j)
            bF[j] = *(const bf16x8*)(gpl + ((size_t)ko * S4_L + j * 16) * 8);
        #pragma unroll
        for (int i = 0; i < 4; ++i)
            #pragma unroll
            for (int j = 0; j < 4; ++j)
                acc[i][j] = __builtin_amdgcn_mfma_f32_16x16x32_bf16(aF[i], bF[j], acc[i][j], 0, 0, 0);
    }
    float* ob = out + (size_t)b * S4_H * S4_L;
    #pragma unroll
    for (int i = 0; i < 4; ++i) {
        #pragma unroll
        for (int jj = 0; jj < 4; ++jj) {
            const int row = m0 + i * 16 + lg * 4 + jj;
            const float bv = bias[row];
            float* orow = ob + (size_t)row * S4_L + l0 + l15;
            #pragma unroll
            for (int j = 0; j < 4; ++j)
                orow[j * 16] = acc[i][j][jj] + bv;
        }
    }
}

extern "C" void kernel_launch(void* const* d_in, const int* in_sizes, int n_in,
                              void* d_out, int out_size, void* d_ws, size_t ws_size,
                              hipStream_t stream) {
    const float* inp        = (const float*)d_in[0]; // (B,CIN,F,L) == (B,H,L)
    const float* log_dt     = (const float*)d_in[1];
    const float* log_A_real = (const float*)d_in[2];
    const float* A_imag     = (const float*)d_in[3];
    const float* C_real     = (const float*)d_in[4];
    const float* C_imag     = (const float*)d_in[5];
    const float* D          = (const float*)d_in[6];
    const float* W_out      = (const float*)d_in[7];
    const float* b_out      = (const float*)d_in[8];
    float* out = (float*)d_out;

    char* wsc = (char*)d_ws;
    size_t off = 0;
    float* wT     = (float*)(wsc + off);  off += (64 << 10);       // 64 KB
    ushort* Ebf   = (ushort*)(wsc + off); off += (2 << 20);        // 2 MB
    ushort* TMbf  = (ushort*)(wsc + off); off += (2 << 20);        // 2 MB
    ushort* Vbf   = (ushort*)(wsc + off); off += (2 << 20);        // 2 MB
    ushort* Wp    = (ushort*)(wsc + off); off += (128 << 10);      // 128 KB
    uint32_t* g   = (uint32_t*)(wsc + off); off += (size_t)S4_B * S4_H * S4_L * 2; // 33.5 MB
    ushort* gP    = (ushort*)(wsc + off);                           // 33.5 MB

    hipLaunchKernelGGL(s4_tab_kernel, dim3(S4_H), dim3(64), 0, stream,
                       log_dt, log_A_real, A_imag, C_real, C_imag, wT, Ebf, TMbf, Vbf);
    hipLaunchKernelGGL(s4_wconv, dim3(32), dim3(256), 0, stream, W_out, Wp);
    hipLaunchKernelGGL(s4_scan_fused, dim3(S4_B * S4_H), dim3(256), 0, stream,
                       inp, wT, Ebf, TMbf, Vbf, D, g);
    hipLaunchKernelGGL(s4_g2p, dim3(32, S4_B), dim3(256), 0, stream,
                       (const ushort*)g, gP);
    hipLaunchKernelGGL(s4_gemm_mfma, dim3(S4_L / 256, S4_H / 64, S4_B), dim3(256), 0, stream,
                       gP, Wp, b_out, out);
}

// Round 6
// 82.597 us; speedup vs baseline: 5.5643x; 1.0343x over previous
//
#include <hip/hip_runtime.h>
#include <hip/hip_bf16.h>
#include <cstdint>

#define S4_H 256
#define S4_N 32
#define S4_L 4096
#define S4_B 16
#define S4_T 64
#define S4_C 64

typedef __attribute__((ext_vector_type(8))) short bf16x8;
typedef __attribute__((ext_vector_type(4))) float f32x4;

// round-to-nearest-even f32 -> bf16 (finite inputs)
__device__ __forceinline__ uint32_t s4_f2bf(float f) {
    uint32_t u = __float_as_uint(f);
    return (u + 0x7fffu + ((u >> 16) & 1u)) >> 16;
}

// tanh-approx GELU: x * sigmoid(1.59577*(x + 0.044715 x^3))
__device__ __forceinline__ float s4_gelu(float x) {
    float x3 = x * x * x;
    float z = 1.5957691216057308f * fmaf(0.044715f, x3, x);
    float e = __expf(-z);
    return x / (1.0f + e);
}

// sum within each 32-lane half via DPP; result valid in lanes 31 and 63
__device__ __forceinline__ float s4_rowsum32(float v) {
    v += __int_as_float(__builtin_amdgcn_update_dpp(0, __float_as_int(v), 0x111, 0xf, 0xf, false)); // row_shr:1
    v += __int_as_float(__builtin_amdgcn_update_dpp(0, __float_as_int(v), 0x112, 0xf, 0xf, false)); // row_shr:2
    v += __int_as_float(__builtin_amdgcn_update_dpp(0, __float_as_int(v), 0x114, 0xf, 0xf, false)); // row_shr:4
    v += __int_as_float(__builtin_amdgcn_update_dpp(0, __float_as_int(v), 0x118, 0xf, 0xf, false)); // row_shr:8
    v += __int_as_float(__builtin_amdgcn_update_dpp(0, __float_as_int(v), 0x142, 0xf, 0xf, false)); // row_bcast15
    return v;
}

// ---------------- table kernel: per-h E, Toeplitz(K), V tables (bf16) + w^T ----------------
__global__ __launch_bounds__(64) void s4_tab_kernel(
        const float* __restrict__ log_dt, const float* __restrict__ log_A_real,
        const float* __restrict__ A_imag, const float* __restrict__ C_real,
        const float* __restrict__ C_imag,
        float* __restrict__ wT, ushort* __restrict__ Ebf,
        ushort* __restrict__ TMbf, ushort* __restrict__ Vbf) {
    const int h = blockIdx.x, tid = threadIdx.x, n = tid & 31;
    __shared__ float Ksh[S4_T];
    const int idx = h * 32 + n;
    float dt = expf(log_dt[h]);
    float Ar = -expf(log_A_real[idx]);
    float Ai = A_imag[idx];
    float er = expf(dt * Ar);
    float wr = er * cosf(dt * Ai);
    float wi = er * sinf(dt * Ai);
    float inv = 1.0f / (Ar * Ar + Ai * Ai);
    float mr = wr - 1.0f, mi = wi;
    float qr = (mr * Ar + mi * Ai) * inv;
    float qi = (mi * Ar - mr * Ai) * inv;
    float Cr = C_real[idx], Ci = C_imag[idx];
    float cr = 2.0f * (Cr * qr - Ci * qi);    //  2*Re(Chat)
    float ci = -2.0f * (Cr * qi + Ci * qr);   // -2*Im(Chat)
    ushort* Eh = Ebf + h * 4096;
    ushort* Vh = Vbf + h * 4096;
    float pr = 1.0f, pi = 0.0f;               // p = w^t
    for (int t = 0; t < S4_T; ++t) {
        if (tid < 32) {
            Eh[(2 * n) * 64 + (63 - t)]     = (ushort)s4_f2bf(pr);
            Eh[(2 * n + 1) * 64 + (63 - t)] = (ushort)s4_f2bf(pi);
        }
        float kt = s4_rowsum32(fmaf(cr, pr, ci * pi));   // K[t] = 2Re(sum Chat w^t)
        if (tid == 31) Ksh[t] = kt;
        float Qr = pr * wr - pi * wi;          // Q = w^{t+1}
        float Qi = pr * wi + pi * wr;
        if (tid < 32) {
            Vh[t * 64 + 2 * n]     = (ushort)s4_f2bf(fmaf(cr, Qr, ci * Qi));   //  2Re(Chat Q)
            Vh[t * 64 + 2 * n + 1] = (ushort)s4_f2bf(fmaf(ci, Qr, -cr * Qi));  // -2Im(Chat Q)
        }
        pr = Qr; pi = Qi;
    }
    if (tid < 32) { wT[idx] = pr; wT[8192 + idx] = pi; }   // w^64
    __syncthreads();
    ushort* TMh = TMbf + h * 4096;
    for (int e = tid; e < 4096; e += 64) {
        int to = e >> 6, ti = e & 63;
        TMh[e] = (ti <= to) ? (ushort)s4_f2bf(Ksh[to - ti]) : (ushort)0;
    }
}

// ---------------- W f32 -> octet-interleaved bf16: Wp[k/8][m][8] ----------------
__global__ __launch_bounds__(256) void s4_wconv(const float* __restrict__ W,
                                               ushort* __restrict__ Wp) {
    const int m = threadIdx.x, ko = blockIdx.x;
    const float* src = W + (size_t)m * S4_H + ko * 8;
    float4 a = *(const float4*)src;
    float4 b = *(const float4*)(src + 4);
    uint4 pk;
    pk.x = s4_f2bf(a.x) | (s4_f2bf(a.y) << 16);
    pk.y = s4_f2bf(a.z) | (s4_f2bf(a.w) << 16);
    pk.z = s4_f2bf(b.x) | (s4_f2bf(b.y) << 16);
    pk.w = s4_f2bf(b.z) | (s4_f2bf(b.w) << 16);
    *(uint4*)(Wp + ((size_t)ko * S4_H + m) * 8) = pk;
}

// ---------------- fused chunk-parallel scan: one block per (b,h) ----------------
// Staging load is lane-contiguous (float4 per lane, 1KB/wave-inst, 100% line use).
__global__ __launch_bounds__(256, 6) void s4_scan_fused(
        const float* __restrict__ u, const float* __restrict__ wT,
        const ushort* __restrict__ Ebf, const ushort* __restrict__ TMbf,
        const ushort* __restrict__ Vbf, const float* __restrict__ D,
        uint32_t* __restrict__ g) {
    __shared__ char UXbfB[8192];       // u as bf16 in phase1; X states in phase2/3
    __shared__ float Ssh[64][66];      // [c][r] chunk sums, padded rows (264B stride)
    const int tid = threadIdx.x;
    const int bh = blockIdx.x;
    const int h = bh & (S4_H - 1);
    const int w = tid >> 6, lane = tid & 63;
    const int l15 = lane & 15, lg = lane >> 4;

    // ---- stage U: 4 coalesced float4 loads per thread -> bf16 LDS ----
    const float* up = u + (size_t)bh * S4_L;
    {
        const float4* uf = (const float4*)up;
        #pragma unroll
        for (int j = 0; j < 4; ++j) {
            int i = j * 256 + tid;           // float4 index; lanes contiguous
            float4 v = uf[i];
            uint2 pk;
            pk.x = s4_f2bf(v.x) | (s4_f2bf(v.y) << 16);
            pk.y = s4_f2bf(v.z) | (s4_f2bf(v.w) << 16);
            int o = i * 8;
            *(uint2*)(UXbfB + (o ^ (((o >> 7) & 7) << 4))) = pk;
        }
    }
    // ---- A-fragments (row = 16w + l15, k0 = lg*8) straight from global (L2-hot) ----
    const int arow = 16 * w + l15;
    const size_t tb = (size_t)h * 4096 + (size_t)arow * 64 + lg * 8;
    bf16x8 eA0 = *(const bf16x8*)(Ebf + tb);
    bf16x8 eA1 = *(const bf16x8*)(Ebf + tb + 32);
    bf16x8 tA0 = *(const bf16x8*)(TMbf + tb);
    bf16x8 tA1 = *(const bf16x8*)(TMbf + tb + 32);
    bf16x8 vA0 = *(const bf16x8*)(Vbf + tb);
    bf16x8 vA1 = *(const bf16x8*)(Vbf + tb + 32);
    __syncthreads();

    // ---- phase 1: S = E @ U; also pull epilogue-u values into regs ----
    bf16x8 ufr[4][2];
    uint2 eu[4];
    const int t0 = 16 * w + lg * 4;
    #pragma unroll
    for (int ct = 0; ct < 4; ++ct) {
        int c = ct * 16 + l15;
        int swz = (c & 7) << 4;
        ufr[ct][0] = *(const bf16x8*)(UXbfB + c * 128 + ((lg * 16) ^ swz));
        ufr[ct][1] = *(const bf16x8*)(UXbfB + c * 128 + ((64 + lg * 16) ^ swz));
        eu[ct] = *(const uint2*)(UXbfB + c * 128 + ((t0 * 2) ^ swz));
        f32x4 acc = {0.f, 0.f, 0.f, 0.f};
        acc = __builtin_amdgcn_mfma_f32_16x16x32_bf16(eA0, ufr[ct][0], acc, 0, 0, 0);
        acc = __builtin_amdgcn_mfma_f32_16x16x32_bf16(eA1, ufr[ct][1], acc, 0, 0, 0);
        *(f32x4*)(&Ssh[c][16 * w + lg * 4]) = acc;   // rows r = 16w + lg*4 + j
    }
    __syncthreads();   // all U reads done -> UXbfB reusable for X

    // ---- phase 3a: Y = TM@U (X-independent) — overlaps with wave0's phase 2 ----
    f32x4 yac[4];
    #pragma unroll
    for (int ct = 0; ct < 4; ++ct) {
        f32x4 y = {0.f, 0.f, 0.f, 0.f};
        y = __builtin_amdgcn_mfma_f32_16x16x32_bf16(tA0, ufr[ct][0], y, 0, 0, 0);
        if (w >= 2)   // Toeplitz rows < 32 have zero k>=32 block: skip the all-zero MFMA
            y = __builtin_amdgcn_mfma_f32_16x16x32_bf16(tA1, ufr[ct][1], y, 0, 0, 0);
        yac[ct] = y;
    }

    // ---- phase 2 (wave 0): X[c] = state before chunk c; x <- wT*x + S[c] ----
    if (tid < 32) {
        float wtr = wT[h * 32 + tid], wti = wT[8192 + h * 32 + tid];
        float xr = 0.f, xi = 0.f;
        #pragma unroll
        for (int c = 0; c < S4_C; ++c) {
            int o = c * 128 + tid * 4;
            *(uint32_t*)(UXbfB + (o ^ (((c & 7) << 4)))) = s4_f2bf(xr) | (s4_f2bf(xi) << 16);
            float2 s2 = *(const float2*)(&Ssh[c][2 * tid]);
            float nr2 = fmaf(wtr, xr, fmaf(-wti, xi, s2.x));
            float ni2 = fmaf(wtr, xi, fmaf(wti, xr, s2.y));
            xr = nr2; xi = ni2;
        }
    }
    __syncthreads();

    // ---- phase 3b: Y += V@X, fused epilogue ----
    const float Dh = D[h];
    uint32_t* gp = g + (size_t)bh * (S4_L / 2);
    #pragma unroll
    for (int ct = 0; ct < 4; ++ct) {
        int c = ct * 16 + l15;
        int swz = (c & 7) << 4;
        bf16x8 xb0 = *(const bf16x8*)(UXbfB + c * 128 + ((lg * 16) ^ swz));
        bf16x8 xb1 = *(const bf16x8*)(UXbfB + c * 128 + ((64 + lg * 16) ^ swz));
        f32x4 y = yac[ct];
        y = __builtin_amdgcn_mfma_f32_16x16x32_bf16(vA0, xb0, y, 0, 0, 0);
        y = __builtin_amdgcn_mfma_f32_16x16x32_bf16(vA1, xb1, y, 0, 0, 0);
        uint2 upk = eu[ct];
        float u0 = __uint_as_float(upk.x << 16);
        float u1 = __uint_as_float(upk.x & 0xffff0000u);
        float u2 = __uint_as_float(upk.y << 16);
        float u3 = __uint_as_float(upk.y & 0xffff0000u);
        float g0 = s4_gelu(fmaf(Dh, u0, y[0]));
        float g1 = s4_gelu(fmaf(Dh, u1, y[1]));
        float g2 = s4_gelu(fmaf(Dh, u2, y[2]));
        float g3 = s4_gelu(fmaf(Dh, u3, y[3]));
        uint2 opk;
        opk.x = s4_f2bf(g0) | (s4_f2bf(g1) << 16);
        opk.y = s4_f2bf(g2) | (s4_f2bf(g3) << 16);
        *(uint2*)(gp + (c * 64 + t0) / 2) = opk;
    }
}

// ---------------- octet transpose: g (B,H,L) -> gP[b][h/8][l][8] (all bf16) ----------------
__global__ __launch_bounds__(256) void s4_g2p(const ushort* __restrict__ g,
                                              ushort* __restrict__ gP) {
    const int ho = blockIdx.x, b = blockIdx.y;
    const int t = threadIdx.x;
    const ushort* gbase = g + (size_t)(b * S4_H + ho * 8) * S4_L;
    ushort* pbase = gP + (size_t)(b * 32 + ho) * S4_L * 8;
    for (int it = 0; it < 8; ++it) {
        int l = it * 512 + t * 2;
        uint32_t r[8];
        #pragma unroll
        for (int i = 0; i < 8; ++i)
            r[i] = *(const uint32_t*)(gbase + (size_t)i * S4_L + l);
        uint4 lo, hi;
        lo.x = (r[0] & 0xffffu) | (r[1] << 16);
        lo.y = (r[2] & 0xffffu) | (r[3] << 16);
        lo.z = (r[4] & 0xffffu) | (r[5] << 16);
        lo.w = (r[6] & 0xffffu) | (r[7] << 16);
        hi.x = (r[0] >> 16) | (r[1] & 0xffff0000u);
        hi.y = (r[2] >> 16) | (r[3] & 0xffff0000u);
        hi.z = (r[4] >> 16) | (r[5] & 0xffff0000u);
        hi.w = (r[6] >> 16) | (r[7] & 0xffff0000u);
        *(uint4*)(pbase + (size_t)l * 8) = lo;       // row l
        *(uint4*)(pbase + (size_t)l * 8 + 8) = hi;   // row l+1
    }
}

// ---------------- LDS-free MFMA GEMM: out[b] = W @ G[b] + bias ----------------
// A-frags from Wp[k/8][m][8], B-frags from gP[b][k/8][l][8]; 4 indep waves/block.
__global__ __launch_bounds__(256) void s4_gemm_mfma(
        const ushort* __restrict__ gP, const ushort* __restrict__ Wp,
        const float* __restrict__ bias, float* __restrict__ out) {
    const int tid = threadIdx.x;
    const int wv = tid >> 6, lane = tid & 63;
    const int l15 = lane & 15, lg = lane >> 4;
    const int b = blockIdx.z;
    const int m0 = blockIdx.y << 6;                       // 64 h' rows per block
    const int l0 = ((blockIdx.x << 2) | wv) << 6;         // 64 l cols per wave
    f32x4 acc[4][4] = {};
    const ushort* wpl = Wp + (size_t)(m0 + l15) * 8;
    const ushort* gpl = gP + ((size_t)(b * 32) * S4_L + l0 + l15) * 8;
    for (int kb = 0; kb < 8; ++kb) {
        const int ko = kb * 4 + lg;                       // k-octet: k = ko*8..ko*8+7
        bf16x8 aF[4], bF[4];
        #pragma unroll
        for (int i = 0; i < 4; ++i)
            aF[i] = *(const bf16x8*)(wpl + ((size_t)ko * S4_H + i * 16) * 8);
        #pragma unroll
        for (int j = 0; j < 4; ++j)
            bF[j] = *(const bf16x8*)(gpl + ((size_t)ko * S4_L + j * 16) * 8);
        #pragma unroll
        for (int i = 0; i < 4; ++i)
            #pragma unroll
            for (int j = 0; j < 4; ++j)
                acc[i][j] = __builtin_amdgcn_mfma_f32_16x16x32_bf16(aF[i], bF[j], acc[i][j], 0, 0, 0);
    }
    float* ob = out + (size_t)b * S4_H * S4_L;
    #pragma unroll
    for (int i = 0; i < 4; ++i) {
        #pragma unroll
        for (int jj = 0; jj < 4; ++jj) {
            const int row = m0 + i * 16 + lg * 4 + jj;
            const float bv = bias[row];
            float* orow = ob + (size_t)row * S4_L + l0 + l15;
            #pragma unroll
            for (int j = 0; j < 4; ++j)
                orow[j * 16] = acc[i][j][jj] + bv;
        }
    }
}

extern "C" void kernel_launch(void* const* d_in, const int* in_sizes, int n_in,
                              void* d_out, int out_size, void* d_ws, size_t ws_size,
                              hipStream_t stream) {
    const float* inp        = (const float*)d_in[0]; // (B,CIN,F,L) == (B,H,L)
    const float* log_dt     = (const float*)d_in[1];
    const float* log_A_real = (const float*)d_in[2];
    const float* A_imag     = (const float*)d_in[3];
    const float* C_real     = (const float*)d_in[4];
    const float* C_imag     = (const float*)d_in[5];
    const float* D          = (const float*)d_in[6];
    const float* W_out      = (const float*)d_in[7];
    const float* b_out      = (const float*)d_in[8];
    float* out = (float*)d_out;

    char* wsc = (char*)d_ws;
    size_t off = 0;
    float* wT     = (float*)(wsc + off);  off += (64 << 10);       // 64 KB
    ushort* Ebf   = (ushort*)(wsc + off); off += (2 << 20);        // 2 MB
    ushort* TMbf  = (ushort*)(wsc + off); off += (2 << 20);        // 2 MB
    ushort* Vbf   = (ushort*)(wsc + off); off += (2 << 20);        // 2 MB
    ushort* Wp    = (ushort*)(wsc + off); off += (128 << 10);      // 128 KB
    uint32_t* g   = (uint32_t*)(wsc + off); off += (size_t)S4_B * S4_H * S4_L * 2; // 33.5 MB
    ushort* gP    = (ushort*)(wsc + off);                           // 33.5 MB

    hipLaunchKernelGGL(s4_tab_kernel, dim3(S4_H), dim3(64), 0, stream,
                       log_dt, log_A_real, A_imag, C_real, C_imag, wT, Ebf, TMbf, Vbf);
    hipLaunchKernelGGL(s4_wconv, dim3(32), dim3(256), 0, stream, W_out, Wp);
    hipLaunchKernelGGL(s4_scan_fused, dim3(S4_B * S4_H), dim3(256), 0, stream,
                       inp, wT, Ebf, TMbf, Vbf, D, g);
    hipLaunchKernelGGL(s4_g2p, dim3(32, S4_B), dim3(256), 0, stream,
                       (const ushort*)g, gP);
    hipLaunchKernelGGL(s4_gemm_mfma, dim3(S4_L / 256, S4_H / 64, S4_B), dim3(256), 0, stream,
                       gP, Wp, b_out, out);
}

// Round 7
// 75.541 us; speedup vs baseline: 6.0841x; 1.0934x over previous
//
#include <hip/hip_runtime.h>
#include <hip/hip_bf16.h>
#include <cstdint>

#define S4_H 256
#define S4_N 32
#define S4_L 4096
#define S4_B 16
#define S4_T 64
#define S4_C 64

typedef __attribute__((ext_vector_type(8))) short bf16x8;
typedef __attribute__((ext_vector_type(4))) float f32x4;

// round-to-nearest-even f32 -> bf16 (finite inputs)
__device__ __forceinline__ uint32_t s4_f2bf(float f) {
    uint32_t u = __float_as_uint(f);
    return (u + 0x7fffu + ((u >> 16) & 1u)) >> 16;
}

// tanh-approx GELU: x * sigmoid(1.59577*(x + 0.044715 x^3))
__device__ __forceinline__ float s4_gelu(float x) {
    float x3 = x * x * x;
    float z = 1.5957691216057308f * fmaf(0.044715f, x3, x);
    float e = __expf(-z);
    return x / (1.0f + e);
}

// sum within each 32-lane half via DPP; result valid in lanes 31 and 63
__device__ __forceinline__ float s4_rowsum32(float v) {
    v += __int_as_float(__builtin_amdgcn_update_dpp(0, __float_as_int(v), 0x111, 0xf, 0xf, false)); // row_shr:1
    v += __int_as_float(__builtin_amdgcn_update_dpp(0, __float_as_int(v), 0x112, 0xf, 0xf, false)); // row_shr:2
    v += __int_as_float(__builtin_amdgcn_update_dpp(0, __float_as_int(v), 0x114, 0xf, 0xf, false)); // row_shr:4
    v += __int_as_float(__builtin_amdgcn_update_dpp(0, __float_as_int(v), 0x118, 0xf, 0xf, false)); // row_shr:8
    v += __int_as_float(__builtin_amdgcn_update_dpp(0, __float_as_int(v), 0x142, 0xf, 0xf, false)); // row_bcast15
    return v;
}

// ---------------- table kernel: per-h E, Toeplitz(K), V tables (bf16) + w^T ----------------
__global__ __launch_bounds__(64) void s4_tab_kernel(
        const float* __restrict__ log_dt, const float* __restrict__ log_A_real,
        const float* __restrict__ A_imag, const float* __restrict__ C_real,
        const float* __restrict__ C_imag,
        float* __restrict__ wT, ushort* __restrict__ Ebf,
        ushort* __restrict__ TMbf, ushort* __restrict__ Vbf) {
    const int h = blockIdx.x, tid = threadIdx.x, n = tid & 31;
    __shared__ float Ksh[S4_T];
    const int idx = h * 32 + n;
    float dt = expf(log_dt[h]);
    float Ar = -expf(log_A_real[idx]);
    float Ai = A_imag[idx];
    float er = expf(dt * Ar);
    float wr = er * cosf(dt * Ai);
    float wi = er * sinf(dt * Ai);
    float inv = 1.0f / (Ar * Ar + Ai * Ai);
    float mr = wr - 1.0f, mi = wi;
    float qr = (mr * Ar + mi * Ai) * inv;
    float qi = (mi * Ar - mr * Ai) * inv;
    float Cr = C_real[idx], Ci = C_imag[idx];
    float cr = 2.0f * (Cr * qr - Ci * qi);    //  2*Re(Chat)
    float ci = -2.0f * (Cr * qi + Ci * qr);   // -2*Im(Chat)
    ushort* Eh = Ebf + h * 4096;
    ushort* Vh = Vbf + h * 4096;
    float pr = 1.0f, pi = 0.0f;               // p = w^t
    for (int t = 0; t < S4_T; ++t) {
        if (tid < 32) {
            Eh[(2 * n) * 64 + (63 - t)]     = (ushort)s4_f2bf(pr);
            Eh[(2 * n + 1) * 64 + (63 - t)] = (ushort)s4_f2bf(pi);
        }
        float kt = s4_rowsum32(fmaf(cr, pr, ci * pi));   // K[t] = 2Re(sum Chat w^t)
        if (tid == 31) Ksh[t] = kt;
        float Qr = pr * wr - pi * wi;          // Q = w^{t+1}
        float Qi = pr * wi + pi * wr;
        if (tid < 32) {
            Vh[t * 64 + 2 * n]     = (ushort)s4_f2bf(fmaf(cr, Qr, ci * Qi));   //  2Re(Chat Q)
            Vh[t * 64 + 2 * n + 1] = (ushort)s4_f2bf(fmaf(ci, Qr, -cr * Qi));  // -2Im(Chat Q)
        }
        pr = Qr; pi = Qi;
    }
    if (tid < 32) { wT[idx] = pr; wT[8192 + idx] = pi; }   // w^64
    __syncthreads();
    ushort* TMh = TMbf + h * 4096;
    for (int e = tid; e < 4096; e += 64) {
        int to = e >> 6, ti = e & 63;
        TMh[e] = (ti <= to) ? (ushort)s4_f2bf(Ksh[to - ti]) : (ushort)0;
    }
}

// ---------------- W f32 -> octet-interleaved bf16: Wp[k/8][m][8] ----------------
__global__ __launch_bounds__(256) void s4_wconv(const float* __restrict__ W,
                                               ushort* __restrict__ Wp) {
    const int m = threadIdx.x, ko = blockIdx.x;
    const float* src = W + (size_t)m * S4_H + ko * 8;
    float4 a = *(const float4*)src;
    float4 b = *(const float4*)(src + 4);
    uint4 pk;
    pk.x = s4_f2bf(a.x) | (s4_f2bf(a.y) << 16);
    pk.y = s4_f2bf(a.z) | (s4_f2bf(a.w) << 16);
    pk.z = s4_f2bf(b.x) | (s4_f2bf(b.y) << 16);
    pk.w = s4_f2bf(b.z) | (s4_f2bf(b.w) << 16);
    *(uint4*)(Wp + ((size_t)ko * S4_H + m) * 8) = pk;
}

// ---------------- fused chunk-parallel scan: one block per (b,h) (unchanged) ----------------
__global__ __launch_bounds__(256, 6) void s4_scan_fused(
        const float* __restrict__ u, const float* __restrict__ wT,
        const ushort* __restrict__ Ebf, const ushort* __restrict__ TMbf,
        const ushort* __restrict__ Vbf, const float* __restrict__ D,
        uint32_t* __restrict__ g) {
    __shared__ char UXbfB[8192];       // u as bf16 in phase1; X states in phase2/3
    __shared__ float Ssh[64][66];      // [c][r] chunk sums, padded rows (264B stride)
    const int tid = threadIdx.x;
    const int bh = blockIdx.x;
    const int h = bh & (S4_H - 1);
    const int w = tid >> 6, lane = tid & 63;
    const int l15 = lane & 15, lg = lane >> 4;

    // ---- stage U: 4 coalesced float4 loads per thread -> bf16 LDS ----
    const float* up = u + (size_t)bh * S4_L;
    {
        const float4* uf = (const float4*)up;
        #pragma unroll
        for (int j = 0; j < 4; ++j) {
            int i = j * 256 + tid;           // float4 index; lanes contiguous
            float4 v = uf[i];
            uint2 pk;
            pk.x = s4_f2bf(v.x) | (s4_f2bf(v.y) << 16);
            pk.y = s4_f2bf(v.z) | (s4_f2bf(v.w) << 16);
            int o = i * 8;
            *(uint2*)(UXbfB + (o ^ (((o >> 7) & 7) << 4))) = pk;
        }
    }
    // ---- A-fragments (row = 16w + l15, k0 = lg*8) straight from global (L2-hot) ----
    const int arow = 16 * w + l15;
    const size_t tb = (size_t)h * 4096 + (size_t)arow * 64 + lg * 8;
    bf16x8 eA0 = *(const bf16x8*)(Ebf + tb);
    bf16x8 eA1 = *(const bf16x8*)(Ebf + tb + 32);
    bf16x8 tA0 = *(const bf16x8*)(TMbf + tb);
    bf16x8 tA1 = *(const bf16x8*)(TMbf + tb + 32);
    bf16x8 vA0 = *(const bf16x8*)(Vbf + tb);
    bf16x8 vA1 = *(const bf16x8*)(Vbf + tb + 32);
    __syncthreads();

    // ---- phase 1: S = E @ U; also pull epilogue-u values into regs ----
    bf16x8 ufr[4][2];
    uint2 eu[4];
    const int t0 = 16 * w + lg * 4;
    #pragma unroll
    for (int ct = 0; ct < 4; ++ct) {
        int c = ct * 16 + l15;
        int swz = (c & 7) << 4;
        ufr[ct][0] = *(const bf16x8*)(UXbfB + c * 128 + ((lg * 16) ^ swz));
        ufr[ct][1] = *(const bf16x8*)(UXbfB + c * 128 + ((64 + lg * 16) ^ swz));
        eu[ct] = *(const uint2*)(UXbfB + c * 128 + ((t0 * 2) ^ swz));
        f32x4 acc = {0.f, 0.f, 0.f, 0.f};
        acc = __builtin_amdgcn_mfma_f32_16x16x32_bf16(eA0, ufr[ct][0], acc, 0, 0, 0);
        acc = __builtin_amdgcn_mfma_f32_16x16x32_bf16(eA1, ufr[ct][1], acc, 0, 0, 0);
        *(f32x4*)(&Ssh[c][16 * w + lg * 4]) = acc;   // rows r = 16w + lg*4 + j
    }
    __syncthreads();   // all U reads done -> UXbfB reusable for X

    // ---- phase 3a: Y = TM@U (X-independent) — overlaps with wave0's phase 2 ----
    f32x4 yac[4];
    #pragma unroll
    for (int ct = 0; ct < 4; ++ct) {
        f32x4 y = {0.f, 0.f, 0.f, 0.f};
        y = __builtin_amdgcn_mfma_f32_16x16x32_bf16(tA0, ufr[ct][0], y, 0, 0, 0);
        if (w >= 2)   // Toeplitz rows < 32 have zero k>=32 block: skip the all-zero MFMA
            y = __builtin_amdgcn_mfma_f32_16x16x32_bf16(tA1, ufr[ct][1], y, 0, 0, 0);
        yac[ct] = y;
    }

    // ---- phase 2 (wave 0): X[c] = state before chunk c; x <- wT*x + S[c] ----
    if (tid < 32) {
        float wtr = wT[h * 32 + tid], wti = wT[8192 + h * 32 + tid];
        float xr = 0.f, xi = 0.f;
        #pragma unroll
        for (int c = 0; c < S4_C; ++c) {
            int o = c * 128 + tid * 4;
            *(uint32_t*)(UXbfB + (o ^ (((c & 7) << 4)))) = s4_f2bf(xr) | (s4_f2bf(xi) << 16);
            float2 s2 = *(const float2*)(&Ssh[c][2 * tid]);
            float nr2 = fmaf(wtr, xr, fmaf(-wti, xi, s2.x));
            float ni2 = fmaf(wtr, xi, fmaf(wti, xr, s2.y));
            xr = nr2; xi = ni2;
        }
    }
    __syncthreads();

    // ---- phase 3b: Y += V@X, fused epilogue ----
    const float Dh = D[h];
    uint32_t* gp = g + (size_t)bh * (S4_L / 2);
    #pragma unroll
    for (int ct = 0; ct < 4; ++ct) {
        int c = ct * 16 + l15;
        int swz = (c & 7) << 4;
        bf16x8 xb0 = *(const bf16x8*)(UXbfB + c * 128 + ((lg * 16) ^ swz));
        bf16x8 xb1 = *(const bf16x8*)(UXbfB + c * 128 + ((64 + lg * 16) ^ swz));
        f32x4 y = yac[ct];
        y = __builtin_amdgcn_mfma_f32_16x16x32_bf16(vA0, xb0, y, 0, 0, 0);
        y = __builtin_amdgcn_mfma_f32_16x16x32_bf16(vA1, xb1, y, 0, 0, 0);
        uint2 upk = eu[ct];
        float u0 = __uint_as_float(upk.x << 16);
        float u1 = __uint_as_float(upk.x & 0xffff0000u);
        float u2 = __uint_as_float(upk.y << 16);
        float u3 = __uint_as_float(upk.y & 0xffff0000u);
        float g0 = s4_gelu(fmaf(Dh, u0, y[0]));
        float g1 = s4_gelu(fmaf(Dh, u1, y[1]));
        float g2 = s4_gelu(fmaf(Dh, u2, y[2]));
        float g3 = s4_gelu(fmaf(Dh, u3, y[3]));
        uint2 opk;
        opk.x = s4_f2bf(g0) | (s4_f2bf(g1) << 16);
        opk.y = s4_f2bf(g2) | (s4_f2bf(g3) << 16);
        *(uint2*)(gp + (c * 64 + t0) / 2) = opk;
    }
}

// ---------------- fused MFMA GEMM: out[b] = W @ G[b] + bias ----------------
// Block = (b, 64-l tile) x all 256 m-rows; G-tile octet-transposed into LDS in
// registers (g2p pattern), XOR-swizzled (ho ^ (l&15)) for conflict-free b128 I/O.
__global__ __launch_bounds__(256) void s4_gemm_mfma(
        const ushort* __restrict__ g,     // bf16 (B,H,L)
        const ushort* __restrict__ Wp,    // octet-interleaved W
        const float* __restrict__ bias, float* __restrict__ out) {
    __shared__ char GlB[32768];           // [64 l][32 ho][8 h] bf16, swizzled
    const int tid = threadIdx.x;
    const int wv = tid >> 6, lane = tid & 63;
    const int l15 = lane & 15, lg = lane >> 4;
    const int b = blockIdx.y;
    const int l0 = blockIdx.x << 6;       // 64 l cols per block

    // ---- stage + octet-transpose G-tile: thread t = (ho, lp) ----
    {
        const int ho = tid >> 3, lp = tid & 7;
        const ushort* gb = g + ((size_t)(b * S4_H) + ho * 8) * S4_L + l0;
        #pragma unroll
        for (int it = 0; it < 4; ++it) {
            const int ll = 2 * (lp + 8 * it);     // even l_local
            uint32_t r[8];
            #pragma unroll
            for (int i = 0; i < 8; ++i)
                r[i] = *(const uint32_t*)(gb + (size_t)i * S4_L + ll);
            uint4 lo, hi;
            lo.x = (r[0] & 0xffffu) | (r[1] << 16);
            lo.y = (r[2] & 0xffffu) | (r[3] << 16);
            lo.z = (r[4] & 0xffffu) | (r[5] << 16);
            lo.w = (r[6] & 0xffffu) | (r[7] << 16);
            hi.x = (r[0] >> 16) | (r[1] & 0xffff0000u);
            hi.y = (r[2] >> 16) | (r[3] & 0xffff0000u);
            hi.z = (r[4] >> 16) | (r[5] & 0xffff0000u);
            hi.w = (r[6] >> 16) | (r[7] & 0xffff0000u);
            *(uint4*)(GlB + ll * 512 + ((ho ^ (ll & 15)) << 4)) = lo;
            *(uint4*)(GlB + (ll + 1) * 512 + ((ho ^ ((ll + 1) & 15)) << 4)) = hi;
        }
    }
    __syncthreads();

    // ---- K-loop: A from Wp (L2-hot), B from LDS; wave wv owns m-rows 64wv.. ----
    f32x4 acc[4][4] = {};
    const ushort* wpl = Wp + (size_t)(64 * wv + l15) * 8;
    #pragma unroll
    for (int kb = 0; kb < 8; ++kb) {
        const int ko = kb * 4 + lg;           // k-octet (= h-octet), k0 = lg*8 in K=32 slice
        bf16x8 aF[4], bF[4];
        #pragma unroll
        for (int i = 0; i < 4; ++i)
            aF[i] = *(const bf16x8*)(wpl + ((size_t)ko * S4_H + i * 16) * 8);
        #pragma unroll
        for (int j = 0; j < 4; ++j)
            bF[j] = *(const bf16x8*)(GlB + (j * 16 + l15) * 512 + ((ko ^ l15) << 4));
        #pragma unroll
        for (int i = 0; i < 4; ++i)
            #pragma unroll
            for (int j = 0; j < 4; ++j)
                acc[i][j] = __builtin_amdgcn_mfma_f32_16x16x32_bf16(aF[i], bF[j], acc[i][j], 0, 0, 0);
    }

    float* ob = out + ((size_t)(b * S4_H) + 64 * wv) * S4_L + l0;
    #pragma unroll
    for (int i = 0; i < 4; ++i) {
        #pragma unroll
        for (int jj = 0; jj < 4; ++jj) {
            const int mrow = i * 16 + lg * 4 + jj;
            const float bv = bias[64 * wv + mrow];
            float* orow = ob + (size_t)mrow * S4_L + l15;
            #pragma unroll
            for (int j = 0; j < 4; ++j)
                orow[j * 16] = acc[i][j][jj] + bv;
        }
    }
}

extern "C" void kernel_launch(void* const* d_in, const int* in_sizes, int n_in,
                              void* d_out, int out_size, void* d_ws, size_t ws_size,
                              hipStream_t stream) {
    const float* inp        = (const float*)d_in[0]; // (B,CIN,F,L) == (B,H,L)
    const float* log_dt     = (const float*)d_in[1];
    const float* log_A_real = (const float*)d_in[2];
    const float* A_imag     = (const float*)d_in[3];
    const float* C_real     = (const float*)d_in[4];
    const float* C_imag     = (const float*)d_in[5];
    const float* D          = (const float*)d_in[6];
    const float* W_out      = (const float*)d_in[7];
    const float* b_out      = (const float*)d_in[8];
    float* out = (float*)d_out;

    char* wsc = (char*)d_ws;
    size_t off = 0;
    float* wT     = (float*)(wsc + off);  off += (64 << 10);       // 64 KB
    ushort* Ebf   = (ushort*)(wsc + off); off += (2 << 20);        // 2 MB
    ushort* TMbf  = (ushort*)(wsc + off); off += (2 << 20);        // 2 MB
    ushort* Vbf   = (ushort*)(wsc + off); off += (2 << 20);        // 2 MB
    ushort* Wp    = (ushort*)(wsc + off); off += (128 << 10);      // 128 KB
    uint32_t* g   = (uint32_t*)(wsc + off);                         // 33.5 MB bf16 (B,H,L)

    hipLaunchKernelGGL(s4_tab_kernel, dim3(S4_H), dim3(64), 0, stream,
                       log_dt, log_A_real, A_imag, C_real, C_imag, wT, Ebf, TMbf, Vbf);
    hipLaunchKernelGGL(s4_wconv, dim3(32), dim3(256), 0, stream, W_out, Wp);
    hipLaunchKernelGGL(s4_scan_fused, dim3(S4_B * S4_H), dim3(256), 0, stream,
                       inp, wT, Ebf, TMbf, Vbf, D, g);
    hipLaunchKernelGGL(s4_gemm_mfma, dim3(S4_L / 64, S4_B), dim3(256), 0, stream,
                       (const ushort*)g, Wp, b_out, out);
}